// Round 2
// baseline (989.710 us; speedup 1.0000x reference)
//
#include <hip/hip_runtime.h>
#include <hip/hip_bf16.h>

typedef __hip_bfloat16 bf16;

#define DEV __device__ __forceinline__

DEV float b2f(bf16 v){ return __bfloat162float(v); }

constexpr int NPIX = 1024;       // 32*32
constexpr int CDIM = 256;
constexpr float EPSF = 1e-5f;
constexpr float LAMBDA_INIT_F = 0.3555090675909693f;   // 0.8 - 0.6*exp(-0.3)
constexpr float ONE_M_LI     = 0.6444909324090307f;
constexpr float ATT_SCALE    = 0.17677669529663687f;   // 32^-0.5

DEV void fma44(float (&acc)[4][4], const float4 a, const float4 c){
  acc[0][0] = fmaf(a.x, c.x, acc[0][0]); acc[0][1] = fmaf(a.x, c.y, acc[0][1]);
  acc[0][2] = fmaf(a.x, c.z, acc[0][2]); acc[0][3] = fmaf(a.x, c.w, acc[0][3]);
  acc[1][0] = fmaf(a.y, c.x, acc[1][0]); acc[1][1] = fmaf(a.y, c.y, acc[1][1]);
  acc[1][2] = fmaf(a.y, c.z, acc[1][2]); acc[1][3] = fmaf(a.y, c.w, acc[1][3]);
  acc[2][0] = fmaf(a.z, c.x, acc[2][0]); acc[2][1] = fmaf(a.z, c.y, acc[2][1]);
  acc[2][2] = fmaf(a.z, c.z, acc[2][2]); acc[2][3] = fmaf(a.z, c.w, acc[2][3]);
  acc[3][0] = fmaf(a.w, c.x, acc[3][0]); acc[3][1] = fmaf(a.w, c.y, acc[3][1]);
  acc[3][2] = fmaf(a.w, c.z, acc[3][2]); acc[3][3] = fmaf(a.w, c.w, acc[3][3]);
}
DEV float dot4(const float4 a, const float4 b){
  return fmaf(a.x,b.x, fmaf(a.y,b.y, fmaf(a.z,b.z, a.w*b.w)));
}

// ================= dtype detect: are inputs f32 or bf16? =================
// Reads x reinterpreted as bf16 halves. f32 random-normal data has random
// mantissa low-halves -> some decode to |v|>1e6 with near-certainty.
// True bf16 data stays small. flag=1 -> inputs are f32.
__global__ __launch_bounds__(256) void detect_kernel(const void* __restrict__ x, int* __restrict__ flag){
  __shared__ int sh;
  if (threadIdx.x == 0) sh = 0;
  __syncthreads();
  const bf16* h = (const bf16*)x;
  int local = 0;
  for (int i = threadIdx.x; i < 4096; i += 256){
    float v = b2f(h[i]);
    if (!(fabsf(v) <= 1e6f)) local = 1;   // catches huge and NaN
  }
  if (local) atomicOr(&sh, 1);
  __syncthreads();
  if (threadIdx.x == 0) *flag = sh;
}

// ================= pack all inputs into one f32 region =================
struct PackArgs { const void* p[34]; };

__global__ __launch_bounds__(256) void pack_kernel(PackArgs args, const int* __restrict__ flagp,
                                                   float* __restrict__ out){
  constexpr int NIN = 34;
  constexpr int off[NIN+1] = {0,1048576,1048832,1049088,1180160,1311232,1442304,1442560,
    1442816,1443072,1443328,1443392,1574464,1574720,1574976,1574984,1771592,1778504,
    1844040,1844296,1844552,1844808,1845064,1845320,1845576,1976648,1977160,1977672,
    1978184,1978696,1979208,1988424,1988936,2120008,2120264};
  const int g = blockIdx.x*256 + threadIdx.x;
  if (g >= off[NIN]) return;
  int idx = 0;
  #pragma unroll
  for (int k = 1; k < NIN; k++) idx = (g >= off[k]) ? k : idx;
  const int local = g - off[idx];
  float v;
  if (*flagp) v = ((const float*)args.p[idx])[local];
  else        v = b2f(((const bf16*)args.p[idx])[local]);
  out[g] = v;
}

// ---------------- LayerNorm over channels (opt. fused BN affine) ----------------
__global__ __launch_bounds__(256) void ln_kernel(
  const float* __restrict__ in, float* __restrict__ out,
  const float* __restrict__ w, const float* __restrict__ bias,
  const float* __restrict__ g, const float* __restrict__ bb,
  const float* __restrict__ m, const float* __restrict__ v, int fuse)
{
  const int p = blockIdx.x*256 + threadIdx.x;
  const int b = p >> 10, pos = p & 1023;
  const float* src = in + (size_t)b*CDIM*NPIX + pos;
  float sum = 0.f, sq = 0.f;
  for (int c = 0; c < CDIM; c++){ float x = src[(size_t)c*NPIX]; sum += x; sq += x*x; }
  const float mean = sum * (1.f/CDIM);
  float var = sq * (1.f/CDIM) - mean*mean; var = fmaxf(var, 0.f);
  const float rstd = rsqrtf(var + EPSF);
  float* dst = out + (size_t)b*CDIM*NPIX + pos;
  for (int c = 0; c < CDIM; c++){
    float x = (src[(size_t)c*NPIX] - mean)*rstd*w[c] + bias[c];
    if (fuse) x = (x - m[c]) * rsqrtf(v[c] + EPSF) * g[c] + bb[c];
    dst[(size_t)c*NPIX] = x;
  }
}

// ---------------- 1x1 conv = GEMM ----------------
// grid: (NPIX/64, Cout/64, B), block 256. 64x64 tile, 4x4 micro-tile/thread.
// FIN: write to d_out with runtime dtype dispatch (flagp).
template<bool BIAS, bool RES, bool FIN>
__global__ __launch_bounds__(256) void conv1x1_kernel(
    const float* __restrict__ in, const float* __restrict__ w,
    const float* __restrict__ bias, const float* __restrict__ res,
    void* __restrict__ outp, int Cin, int Cout, const int* __restrict__ flagp)
{
  __shared__ __align__(16) float wt[64][68];   // [k][o]
  __shared__ __align__(16) float it[64][68];   // [k][p]
  const int t  = threadIdx.x;
  const int to = t & 15, tp = t >> 4;
  const int pb = blockIdx.x*64, ob = blockIdx.y*64, b = blockIdx.z;
  const int so = t >> 2, s0 = (t & 3) * 16;
  float acc[4][4] = {};
  for (int kb = 0; kb < Cin; kb += 64){
    const float* wp = w  + (size_t)(ob + so)*Cin + kb + s0;
    const float* ip = in + ((size_t)b*Cin + kb + so)*NPIX + pb + s0;
    #pragma unroll
    for (int j = 0; j < 16; j++) wt[s0+j][so] = wp[j];
    #pragma unroll
    for (int j = 0; j < 16; j++) it[so][s0+j] = ip[j];
    __syncthreads();
    #pragma unroll 8
    for (int ik = 0; ik < 64; ik++){
      const float4 a = *(const float4*)&wt[ik][4*to];
      const float4 c = *(const float4*)&it[ik][4*tp];
      fma44(acc, a, c);
    }
    __syncthreads();
  }
  #pragma unroll
  for (int i = 0; i < 4; i++){
    const int o = ob + 4*to + i;
    const size_t row = ((size_t)b*Cout + o)*NPIX + pb + 4*tp;
    const float bv = BIAS ? bias[o] : 0.f;
    float4 r = make_float4(0.f,0.f,0.f,0.f);
    if (RES) r = *(const float4*)&res[row];
    const float v0 = acc[i][0] + bv + r.x;
    const float v1 = acc[i][1] + bv + r.y;
    const float v2 = acc[i][2] + bv + r.z;
    const float v3 = acc[i][3] + bv + r.w;
    if (FIN){
      if (*flagp){
        *(float4*)&(((float*)outp)[row]) = make_float4(v0,v1,v2,v3);
      } else {
        bf16* ob16 = (bf16*)outp;
        ob16[row+0] = __float2bfloat16(v0); ob16[row+1] = __float2bfloat16(v1);
        ob16[row+2] = __float2bfloat16(v2); ob16[row+3] = __float2bfloat16(v3);
      }
    } else {
      *(float4*)&(((float*)outp)[row]) = make_float4(v0,v1,v2,v3);
    }
  }
}

// ---------------- CDA differential attention ----------------
// grid: (16 q-tiles, NH=8, B=4), block 256. Q/K layout (B, NH*64, NPIX).
__global__ __launch_bounds__(256) void cda_attn_kernel(
  const float* __restrict__ Q, const float* __restrict__ K, const float* __restrict__ V,
  const float* __restrict__ lq1, const float* __restrict__ lk1,
  const float* __restrict__ lq2, const float* __restrict__ lk2,
  const float* __restrict__ rms_scale, float* __restrict__ att)
{
  __shared__ __align__(16) float Qs[64][68];   // [d][q]
  __shared__ __align__(16) float Ks[64][68];   // [d][m]
  __shared__ __align__(16) float Ps[64][68];   // [q][m]
  __shared__ float zpart[64][17];
  __shared__ float Zs[2][64];
  __shared__ float rinv[64];
  __shared__ float lam_s;
  const int t = threadIdx.x;
  const int qb = blockIdx.x*64, h = blockIdx.y, b = blockIdx.z;
  const size_t base = ((size_t)b*512 + h*64)*NPIX;
  const int sd = t >> 2, s0 = (t & 3) * 16;
  { const float* qp = Q + base + (size_t)sd*NPIX + qb + s0;
    #pragma unroll
    for (int j = 0; j < 16; j++) Qs[sd][s0+j] = qp[j]; }
  if (t == 0){
    float a = 0.f, c2 = 0.f;
    for (int i = 0; i < 32; i++){
      a  += lq1[h*32+i] * lk1[h*32+i];
      c2 += lq2[h*32+i] * lk2[h*32+i];
    }
    lam_s = __expf(a) - __expf(c2) + LAMBDA_INIT_F;
  }
  if (t < 64){ Zs[0][t] = 0.f; Zs[1][t] = 0.f; }
  const int qg = t >> 4, xg = t & 15;   // xg: m-group in scores, d-group in PV
  float acc[2][4][4] = {};
  for (int mb = 0; mb < NPIX; mb += 64){
    { const float* kp = K + base + (size_t)sd*NPIX + mb + s0;
      #pragma unroll
      for (int j = 0; j < 16; j++) Ks[sd][s0+j] = kp[j]; }
    __syncthreads();
    #pragma unroll
    for (int hx = 0; hx < 2; hx++){
      float sc[4][4] = {};
      const int dbase = hx*32;
      #pragma unroll 8
      for (int d = 0; d < 32; d++){
        const float4 a = *(const float4*)&Qs[dbase+d][4*qg];
        const float4 c = *(const float4*)&Ks[dbase+d][4*xg];
        fma44(sc, a, c);
      }
      #pragma unroll
      for (int i = 0; i < 4; i++){
        float zp = 0.f;
        #pragma unroll
        for (int j = 0; j < 4; j++){
          const float e = __expf(sc[i][j]*ATT_SCALE);
          Ps[4*qg+i][4*xg+j] = e; zp += e;
        }
        zpart[4*qg+i][xg] = zp;
      }
      __syncthreads();
      if (t < 64){
        float s = 0.f;
        #pragma unroll
        for (int g2 = 0; g2 < 16; g2++) s += zpart[t][g2];
        Zs[hx][t] += s;
      }
      const float* Vg = V + base + mb;
      #pragma unroll 4
      for (int mq = 0; mq < 64; mq += 4){
        const float4 p0 = *(const float4*)&Ps[4*qg+0][mq];
        const float4 p1 = *(const float4*)&Ps[4*qg+1][mq];
        const float4 p2 = *(const float4*)&Ps[4*qg+2][mq];
        const float4 p3 = *(const float4*)&Ps[4*qg+3][mq];
        const float4 v0 = *(const float4*)&Vg[(size_t)(4*xg+0)*NPIX + mq];
        const float4 v1 = *(const float4*)&Vg[(size_t)(4*xg+1)*NPIX + mq];
        const float4 v2 = *(const float4*)&Vg[(size_t)(4*xg+2)*NPIX + mq];
        const float4 v3 = *(const float4*)&Vg[(size_t)(4*xg+3)*NPIX + mq];
        acc[hx][0][0] += dot4(p0,v0); acc[hx][0][1] += dot4(p0,v1);
        acc[hx][0][2] += dot4(p0,v2); acc[hx][0][3] += dot4(p0,v3);
        acc[hx][1][0] += dot4(p1,v0); acc[hx][1][1] += dot4(p1,v1);
        acc[hx][1][2] += dot4(p1,v2); acc[hx][1][3] += dot4(p1,v3);
        acc[hx][2][0] += dot4(p2,v0); acc[hx][2][1] += dot4(p2,v1);
        acc[hx][2][2] += dot4(p2,v2); acc[hx][2][3] += dot4(p2,v3);
        acc[hx][3][0] += dot4(p3,v0); acc[hx][3][1] += dot4(p3,v1);
        acc[hx][3][2] += dot4(p3,v2); acc[hx][3][3] += dot4(p3,v3);
      }
      __syncthreads();
    }
  }
  float o[4][4];
  const float lam = lam_s;
  #pragma unroll
  for (int i = 0; i < 4; i++){
    const int q = 4*qg + i;
    const float iz0 = 1.f/Zs[0][q], iz1 = 1.f/Zs[1][q];
    float ss = 0.f;
    #pragma unroll
    for (int j = 0; j < 4; j++){
      const float v = acc[0][i][j]*iz0 - lam*acc[1][i][j]*iz1;
      o[i][j] = v; ss += v*v;
    }
    zpart[q][xg] = ss;
  }
  __syncthreads();
  if (t < 64){
    float s = 0.f;
    #pragma unroll
    for (int g2 = 0; g2 < 16; g2++) s += zpart[t][g2];
    rinv[t] = ONE_M_LI * rsqrtf(s*(1.f/64.f) + EPSF);
  }
  __syncthreads();
  #pragma unroll
  for (int i = 0; i < 4; i++){
    const int q = 4*qg + i;
    const float rv = rinv[q];
    #pragma unroll
    for (int j = 0; j < 4; j++){
      const int d = 4*xg + j;
      att[base + (size_t)d*NPIX + qb + q] = o[i][j]*rv*rms_scale[d];
    }
  }
}

// ---------------- depthwise 3x3 (768 channels, SAME) ----------------
__global__ void dwconv3_kernel(const float* __restrict__ in, const float* __restrict__ w,
                               float* __restrict__ out){
  const int gIdx = blockIdx.x*256 + threadIdx.x;
  const int x = gIdx & 31, y = (gIdx >> 5) & 31;
  const int plane = gIdx >> 10;
  const int c = plane % 768;
  const float* ip = in + (size_t)plane*NPIX;
  float s = 0.f;
  #pragma unroll
  for (int ky = 0; ky < 3; ky++){
    const int yy = y + ky - 1;
    if (yy < 0 || yy > 31) continue;
    #pragma unroll
    for (int kx = 0; kx < 3; kx++){
      const int xx = x + kx - 1;
      if (xx < 0 || xx > 31) continue;
      s = fmaf(ip[yy*32+xx], w[c*9 + ky*3 + kx], s);
    }
  }
  out[gIdx] = s;
}

// ---------------- L2-normalize rows over spatial dim (CHA q,k) ----------------
__global__ __launch_bounds__(256) void l2norm_kernel(float* __restrict__ x){
  const int r = blockIdx.x;
  const int b = r >> 9, c = r & 511;
  float* p = x + ((size_t)b*768 + c)*NPIX;
  const int t = threadIdx.x;
  float4 v = ((float4*)p)[t];
  float s = v.x*v.x + v.y*v.y + v.z*v.z + v.w*v.w;
  for (int off = 32; off; off >>= 1) s += __shfl_down(s, off);
  __shared__ float wsum[4];
  if ((t & 63) == 0) wsum[t >> 6] = s;
  __syncthreads();
  const float tot = wsum[0] + wsum[1] + wsum[2] + wsum[3];
  const float inv = 1.f / fmaxf(sqrtf(tot), 1e-12f);
  ((float4*)p)[t] = make_float4(v.x*inv, v.y*inv, v.z*inv, v.w*inv);
}

// ---------------- CHA partial scores ----------------
__global__ __launch_bounds__(256) void cha_scores_kernel(const float* __restrict__ qk,
                                                         float* __restrict__ spart){
  __shared__ float qs[32][129];
  __shared__ float ks[32][129];
  const int t = threadIdx.x;
  const int nb = blockIdx.x*128;
  const int bh = blockIdx.y, b = bh >> 3, h = bh & 7;
  const size_t qbase = ((size_t)b*768 + h*32)*NPIX + nb;
  const size_t kbase = qbase + (size_t)256*NPIX;
  { const int c = t >> 3, n0 = (t & 7)*16;
    #pragma unroll
    for (int j = 0; j < 16; j++){
      qs[c][n0+j] = qk[qbase + (size_t)c*NPIX + n0 + j];
      ks[c][n0+j] = qk[kbase + (size_t)c*NPIX + n0 + j];
    } }
  __syncthreads();
  const int c = t & 31, dg = t >> 5;
  float acc[4] = {};
  for (int nn = 0; nn < 128; nn++){
    const float qv = qs[c][nn];
    #pragma unroll
    for (int j = 0; j < 4; j++) acc[j] = fmaf(qv, ks[dg*4+j][nn], acc[j]);
  }
  float* sp = spart + ((size_t)bh*8 + blockIdx.x)*1024 + c*32 + dg*4;
  #pragma unroll
  for (int j = 0; j < 4; j++) sp[j] = acc[j];
}

// ---------------- CHA softmax over d (32x32 per head) ----------------
__global__ void cha_softmax_kernel(const float* __restrict__ spart,
                                   const float* __restrict__ temp, float* __restrict__ P){
  __shared__ float Ss[32][33];
  const int t = threadIdx.x;
  const int bh = blockIdx.x, h = bh & 7;
  const float tf = temp[h];
  for (int p = t*4; p < t*4+4; p++){
    float s = 0.f;
    for (int ch = 0; ch < 8; ch++) s += spart[((size_t)bh*8 + ch)*1024 + p];
    Ss[p >> 5][p & 31] = s * tf;
  }
  __syncthreads();
  if (t < 32){
    float mx = -1e30f;
    for (int d = 0; d < 32; d++) mx = fmaxf(mx, Ss[t][d]);
    float sum = 0.f;
    for (int d = 0; d < 32; d++){ const float e = __expf(Ss[t][d]-mx); Ss[t][d] = e; sum += e; }
    const float inv = 1.f/sum;
    for (int d = 0; d < 32; d++) P[(size_t)bh*1024 + t*32 + d] = Ss[t][d]*inv;
  }
}

// ---------------- CHA PV ----------------
__global__ __launch_bounds__(256) void cha_pv_kernel(const float* __restrict__ P,
                                                     const float* __restrict__ qkv,
                                                     float* __restrict__ out){
  __shared__ float Ps[32][33];
  const int t = threadIdx.x;
  const int bh = blockIdx.y, b = bh >> 3, h = bh & 7;
  const int nb = blockIdx.x*64;
  for (int p = t; p < 1024; p += 256) Ps[p >> 5][p & 31] = P[(size_t)bh*1024 + p];
  __syncthreads();
  const int n = nb + (t & 63);
  const int cg = t >> 6;
  const size_t vbase = ((size_t)b*768 + 512 + h*32)*NPIX + n;
  float acc[8] = {};
  for (int d = 0; d < 32; d++){
    const float v = qkv[vbase + (size_t)d*NPIX];
    #pragma unroll
    for (int j = 0; j < 8; j++) acc[j] = fmaf(Ps[cg*8+j][d], v, acc[j]);
  }
  const size_t obase = ((size_t)b*256 + h*32 + cg*8)*NPIX + n;
  #pragma unroll
  for (int j = 0; j < 8; j++) out[obase + (size_t)j*NPIX] = acc[j];
}

// ---------------- BN2 affine (512 channels), in-place ----------------
__global__ void bn_affine_kernel(float* __restrict__ x, const float* __restrict__ g,
                                 const float* __restrict__ b, const float* __restrict__ m,
                                 const float* __restrict__ v){
  const int i = blockIdx.x*256 + threadIdx.x;
  const int c = (i >> 10) & 511;
  x[i] = (x[i] - m[c]) * rsqrtf(v[c] + EPSF) * g[c] + b[c];
}

// ---------------- FFN grouped 3x3 + bias + relu6 ----------------
__global__ void gconv3_kernel(const float* __restrict__ in, const float* __restrict__ w,
                              const float* __restrict__ bias, float* __restrict__ out){
  const int gIdx = blockIdx.x*256 + threadIdx.x;
  const int x = gIdx & 31, y = (gIdx >> 5) & 31;
  const int plane = gIdx >> 10;
  const int o = plane & 511, b = plane >> 9;
  const float* ip = in + ((size_t)b*512 + (o & ~1))*NPIX;
  float s = bias[o];
  #pragma unroll
  for (int ci = 0; ci < 2; ci++){
    #pragma unroll
    for (int ky = 0; ky < 3; ky++){
      const int yy = y + ky - 1;
      if (yy < 0 || yy > 31) continue;
      #pragma unroll
      for (int kx = 0; kx < 3; kx++){
        const int xx = x + kx - 1;
        if (xx < 0 || xx > 31) continue;
        s = fmaf(ip[(size_t)ci*NPIX + yy*32+xx], w[o*18 + ci*9 + ky*3 + kx], s);
      }
    }
  }
  out[gIdx] = fminf(fmaxf(s, 0.f), 6.f);
}

extern "C" void kernel_launch(void* const* d_in, const int* in_sizes, int n_in,
                              void* d_out, int out_size, void* d_ws, size_t ws_size,
                              hipStream_t stream)
{
  (void)in_sizes; (void)n_in; (void)out_size; (void)ws_size;

  float* ws = (float*)d_ws;
  float* P  = ws;                       // packed f32 inputs (2120264 floats); x at offset 0
  float* xbuf  = P;                     // residual buffer == packed x
  float* hbuf  = ws + 2120704;          // 1048576
  float* abuf  = ws + 3169280;          // 6291456 (Q,K,V / qkv / ffn f1 / cha out)
  float* bbuf  = ws + 9460736;          // 3145728 (att out / dw out / ffn f2)
  float* spart = ws + 12606464;         // 262144
  float* pbuf  = ws + 12868608;         // 32768
  int*   flag  = (int*)(ws + 12901376);

  // packed-region parameter pointers
  const float* ln1w = P+1048576; const float* ln1b = P+1048832;
  const float* wq   = P+1049088; const float* wk   = P+1180160; const float* wv = P+1311232;
  const float* lq1  = P+1442304; const float* lk1  = P+1442560;
  const float* lq2  = P+1442816; const float* lk2  = P+1443072;
  const float* rmss = P+1443328; const float* wo   = P+1443392;
  const float* ln2w = P+1574464; const float* ln2b = P+1574720;
  const float* temp = P+1574976; const float* wqkv = P+1574984;
  const float* wdw  = P+1771592; const float* wout = P+1778504;
  const float* ln3w = P+1844040; const float* ln3b = P+1844296;
  const float* bn1g = P+1844552; const float* bn1b = P+1844808;
  const float* bn1m = P+1845064; const float* bn1v = P+1845320;
  const float* w1   = P+1845576; const float* b1   = P+1976648;
  const float* bn2g = P+1977160; const float* bn2b = P+1977672;
  const float* bn2m = P+1978184; const float* bn2v = P+1978696;
  const float* w2   = P+1979208; const float* b2   = P+1988424;
  const float* w3   = P+1988936; const float* b3   = P+2120008;

  float* Qb = abuf;
  float* Kb = abuf + 2097152;
  float* Vb = abuf + 4194304;

  // detect dtype + pack all inputs to f32
  detect_kernel<<<1, 256, 0, stream>>>(d_in[0], flag);
  PackArgs pa;
  for (int i = 0; i < 34; i++) pa.p[i] = d_in[i];
  pack_kernel<<<8283, 256, 0, stream>>>(pa, flag, P);

  const dim3 g512(16, 8, 4), g256(16, 4, 4), g768(16, 12, 4);

  // ---- CDA branch ----
  ln_kernel<<<16, 256, 0, stream>>>(xbuf, hbuf, ln1w, ln1b, ln1w, ln1w, ln1w, ln1w, 0);
  conv1x1_kernel<false,false,false><<<g512, 256, 0, stream>>>(hbuf, wq, nullptr, nullptr, Qb, 256, 512, nullptr);
  conv1x1_kernel<false,false,false><<<g512, 256, 0, stream>>>(hbuf, wk, nullptr, nullptr, Kb, 256, 512, nullptr);
  conv1x1_kernel<false,false,false><<<g512, 256, 0, stream>>>(hbuf, wv, nullptr, nullptr, Vb, 256, 512, nullptr);
  cda_attn_kernel<<<dim3(16,8,4), 256, 0, stream>>>(Qb, Kb, Vb, lq1, lk1, lq2, lk2, rmss, bbuf);
  conv1x1_kernel<false,true,false><<<g256, 256, 0, stream>>>(bbuf, wo, nullptr, xbuf, xbuf, 512, 256, nullptr);

  // ---- CHA branch ----
  ln_kernel<<<16, 256, 0, stream>>>(xbuf, hbuf, ln2w, ln2b, ln1w, ln1w, ln1w, ln1w, 0);
  conv1x1_kernel<false,false,false><<<g768, 256, 0, stream>>>(hbuf, wqkv, nullptr, nullptr, abuf, 256, 768, nullptr);
  dwconv3_kernel<<<12288, 256, 0, stream>>>(abuf, wdw, bbuf);
  l2norm_kernel<<<2048, 256, 0, stream>>>(bbuf);
  cha_scores_kernel<<<dim3(8,32), 256, 0, stream>>>(bbuf, spart);
  cha_softmax_kernel<<<32, 256, 0, stream>>>(spart, temp, pbuf);
  cha_pv_kernel<<<dim3(16,32), 256, 0, stream>>>(pbuf, bbuf, abuf);
  conv1x1_kernel<false,true,false><<<g256, 256, 0, stream>>>(abuf, wout, nullptr, xbuf, xbuf, 256, 256, nullptr);

  // ---- FFN branch ----
  ln_kernel<<<16, 256, 0, stream>>>(xbuf, hbuf, ln3w, ln3b, bn1g, bn1b, bn1m, bn1v, 1);
  conv1x1_kernel<true,false,false><<<g512, 256, 0, stream>>>(hbuf, w1, b1, nullptr, abuf, 256, 512, nullptr);
  bn_affine_kernel<<<8192, 256, 0, stream>>>(abuf, bn2g, bn2b, bn2m, bn2v);
  gconv3_kernel<<<8192, 256, 0, stream>>>(abuf, w2, b2, bbuf);
  conv1x1_kernel<true,true,true><<<g256, 256, 0, stream>>>(bbuf, w3, b3, xbuf, d_out, 512, 256, flag);
}

// Round 3
// 373.306 us; speedup vs baseline: 2.6512x; 2.6512x over previous
//
#include <hip/hip_runtime.h>
#include <hip/hip_bf16.h>

typedef __hip_bfloat16 bf16;
typedef __attribute__((ext_vector_type(8))) short s16x8;
typedef __attribute__((ext_vector_type(4))) float f32x4;

#define DEV __device__ __forceinline__

DEV float b2f(bf16 v){ return __bfloat162float(v); }
DEV ushort f2bf(float f){ bf16 h = __float2bfloat16(f); return *reinterpret_cast<ushort*>(&h); }
DEV float bf2f(ushort u){ bf16 h; *reinterpret_cast<ushort*>(&h) = u; return __bfloat162float(h); }

constexpr int NPIX = 1024;
constexpr float EPSF = 1e-5f;
constexpr float LAMBDA_INIT_F = 0.3555090675909693f;   // 0.8 - 0.6*exp(-0.3)
constexpr float ONE_M_LI     = 0.6444909324090307f;
constexpr float ATT_SCALE    = 0.17677669529663687f;   // 32^-0.5

// workspace offsets (in floats)
constexpr size_t OFF_WBF   = 2120448;   // bf16 weights, 1048576 elems
constexpr size_t OFF_QT    = 2644736;   // QT/KT bf16 [2][4][8][1024][64]
constexpr size_t OFF_V16   = 4741888;   // V bf16 [4][512][1024]
constexpr size_t OFF_ATT   = 5790464;   // att bf16 [4][1024][512]; later chaout f32
constexpr size_t OFF_BUF1  = 6839040;   // f32 [4][768][1024] qkv / ffn1
constexpr size_t OFF_BUF2  = 9984768;   // f32 dw / gconv out
constexpr size_t OFF_SPART = 13130496;
constexpr size_t OFF_PBUF  = 13392640;
constexpr size_t OFF_STATS = 13425408;  // mu1,r1,mu2,r2,mu3,r3 (6*4096)
constexpr size_t OFF_EFF   = 13449984;  // effw1,effb1,effw2,effb2,effw3,effb3(256 ea), s2(512), t2(512)
constexpr size_t OFF_FLAG  = 13452544;

// ---------------- dtype detect ----------------
__global__ __launch_bounds__(256) void detect_kernel(const void* __restrict__ x, int* __restrict__ flag){
  __shared__ int sh;
  if (threadIdx.x == 0) sh = 0;
  __syncthreads();
  const bf16* h = (const bf16*)x;
  int local = 0;
  for (int i = threadIdx.x; i < 4096; i += 256){
    float v = b2f(h[i]);
    if (!(fabsf(v) <= 1e6f)) local = 1;
  }
  if (local) atomicOr(&sh, 1);
  __syncthreads();
  if (threadIdx.x == 0) *flag = sh;
}

// ---------------- pack all inputs to f32 ----------------
struct PackArgs { const void* p[34]; };

__global__ __launch_bounds__(256) void pack_kernel(PackArgs args, const int* __restrict__ flagp,
                                                   float* __restrict__ out){
  constexpr int NIN = 34;
  constexpr int off[NIN+1] = {0,1048576,1048832,1049088,1180160,1311232,1442304,1442560,
    1442816,1443072,1443328,1443392,1574464,1574720,1574976,1574984,1771592,1778504,
    1844040,1844296,1844552,1844808,1845064,1845320,1845576,1976648,1977160,1977672,
    1978184,1978696,1979208,1988424,1988936,2120008,2120264};
  const int g = blockIdx.x*256 + threadIdx.x;
  if (g >= off[NIN]) return;
  int idx = 0;
  #pragma unroll
  for (int k = 1; k < NIN; k++) idx = (g >= off[k]) ? k : idx;
  const int local = g - off[idx];
  float v;
  if (*flagp) v = ((const float*)args.p[idx])[local];
  else        v = b2f(((const bf16*)args.p[idx])[local]);
  out[g] = v;
}

// ---------------- bf16 weight pack (6 contiguous slices of P) ----------------
__global__ __launch_bounds__(256) void wpack_kernel(const float* __restrict__ P, ushort* __restrict__ W){
  const int g = blockIdx.x*256 + threadIdx.x;   // < 1048576
  int src;
  if      (g <  393216) src = 1049088 + g;               // wq|wk|wv  [1536][256]
  else if (g <  589824) src = 1574984 + (g - 393216);    // wqkv      [768][256]
  else if (g <  720896) src = 1443392 + (g - 589824);    // wo        [256][512]
  else if (g <  786432) src = 1778504 + (g - 720896);    // wout      [256][256]
  else if (g <  917504) src = 1845576 + (g - 786432);    // w1        [512][256]
  else                  src = 1988936 + (g - 917504);    // w3        [256][512]
  W[g] = f2bf(P[src]);
}

// ---------------- per-channel folded params ----------------
__global__ __launch_bounds__(256) void prep_kernel(const float* __restrict__ P, float* __restrict__ eff){
  const int t = threadIdx.x;
  eff[t]      = P[1048576+t];  eff[256+t]  = P[1048832+t];            // ln1
  eff[512+t]  = P[1574464+t];  eff[768+t]  = P[1574720+t];            // ln2
  const float s1 = P[1844552+t] * rsqrtf(P[1845320+t] + EPSF);        // bn1g*rsqrt(bn1v)
  eff[1024+t] = P[1844040+t] * s1;                                    // ln3w*s1
  eff[1280+t] = (P[1844296+t] - P[1845064+t]) * s1 + P[1844808+t];    // (ln3b-bn1m)*s1+bn1b
  for (int c = t; c < 512; c += 256){
    const float sc = P[1977160+c] * rsqrtf(P[1978696+c] + EPSF);      // bn2
    eff[1536+c] = sc;
    eff[2048+c] = P[1977672+c] - P[1978184+c]*sc;
  }
}

// ---------------- LN stats: mu, rstd per (b, n) ----------------
__global__ __launch_bounds__(256) void ln_stats_kernel(const float* __restrict__ x,
    float* __restrict__ mu, float* __restrict__ rstd){
  __shared__ float ps[16][64], ps2[16][64];
  const int t = threadIdx.x;
  const int b = blockIdx.x >> 4, n0 = (blockIdx.x & 15)*64;
  const int tn = t & 15, tc = t >> 4;
  float4 s = {0,0,0,0}, q = {0,0,0,0};
  #pragma unroll
  for (int i = 0; i < 16; i++){
    const int c = tc*16 + i;
    const float4 v = *(const float4*)&x[((size_t)b*256 + c)*NPIX + n0 + tn*4];
    s.x += v.x; s.y += v.y; s.z += v.z; s.w += v.w;
    q.x += v.x*v.x; q.y += v.y*v.y; q.z += v.z*v.z; q.w += v.w*v.w;
  }
  ps[tc][tn*4+0]=s.x; ps[tc][tn*4+1]=s.y; ps[tc][tn*4+2]=s.z; ps[tc][tn*4+3]=s.w;
  ps2[tc][tn*4+0]=q.x; ps2[tc][tn*4+1]=q.y; ps2[tc][tn*4+2]=q.z; ps2[tc][tn*4+3]=q.w;
  __syncthreads();
  if (t < 64){
    float a = 0.f, qq = 0.f;
    #pragma unroll
    for (int j = 0; j < 16; j++){ a += ps[j][t]; qq += ps2[j][t]; }
    const float m = a * (1.f/256.f);
    float var = qq * (1.f/256.f) - m*m; var = fmaxf(var, 0.f);
    mu[(size_t)b*NPIX + n0 + t] = m;
    rstd[(size_t)b*NPIX + n0 + t] = rsqrtf(var + EPSF);
  }
}

// ---------------- unified MFMA GEMM ----------------
// IN modes: 0 = f32 [c][n] + LN; 1 = f32 [c][n] plain; 2 = bf16 [b][n][Cin]
// EPI modes: 0 = QKV special; 1 = f32 +res; 2 = f32 (+bias)(+bn2); 3 = final out
template<int INM, int EPIM, bool BIAS, bool BN2F>
__global__ __launch_bounds__(256) void gemm_kernel(
    const float* __restrict__ Xf, const ushort* __restrict__ Xb, const ushort* __restrict__ W,
    const float* __restrict__ bias, const float* __restrict__ mu, const float* __restrict__ rstd,
    const float* __restrict__ effw, const float* __restrict__ effb,
    const float* __restrict__ s2, const float* __restrict__ t2,
    const float* __restrict__ res, void* __restrict__ out,
    ushort* __restrict__ qt, ushort* __restrict__ v16,
    int Cin, const int* __restrict__ flag)
{
  __shared__ ushort Xt[64][72];
  const int t = threadIdx.x;
  const int nb = blockIdx.x*64, ob = blockIdx.y*64, b = blockIdx.z;
  const int lane = t & 63, w = t >> 6;
  const int wR = w >> 1, wC = w & 1;
  const int l15 = lane & 15, g = lane >> 4;
  const int tn = t & 63, tc4 = t >> 6;
  const f32x4 z4 = {0.f,0.f,0.f,0.f};
  f32x4 acc[2][2] = {{z4,z4},{z4,z4}};

  for (int kb = 0; kb < Cin; kb += 64){
    if (INM == 2){
      const ushort* src = Xb + ((size_t)b*NPIX + nb + tn)*Cin + kb + tc4*16;
      *(uint4*)&Xt[tn][tc4*16]   = *(const uint4*)src;
      *(uint4*)&Xt[tn][tc4*16+8] = *(const uint4*)(src+8);
    } else {
      float m_ = 0.f, r_ = 1.f;
      if (INM == 0){ m_ = mu[(size_t)b*NPIX + nb + tn]; r_ = rstd[(size_t)b*NPIX + nb + tn]; }
      ushort tmp[16];
      #pragma unroll
      for (int i = 0; i < 16; i++){
        const int c = kb + tc4*16 + i;
        float v = Xf[((size_t)b*Cin + c)*NPIX + nb + tn];
        if (INM == 0) v = (v - m_)*r_*effw[c] + effb[c];
        tmp[i] = f2bf(v);
      }
      *(uint4*)&Xt[tn][tc4*16]   = *(uint4*)&tmp[0];
      *(uint4*)&Xt[tn][tc4*16+8] = *(uint4*)&tmp[8];
    }
    __syncthreads();
    #pragma unroll
    for (int ks = 0; ks < 2; ks++){
      const s16x8 a0 = *(const s16x8*)&W[(size_t)(ob + wR*32 + l15)*Cin + kb + ks*32 + g*8];
      const s16x8 a1 = *(const s16x8*)&W[(size_t)(ob + wR*32 + 16 + l15)*Cin + kb + ks*32 + g*8];
      const s16x8 b0 = *(const s16x8*)&Xt[wC*32 + l15][ks*32 + g*8];
      const s16x8 b1 = *(const s16x8*)&Xt[wC*32 + 16 + l15][ks*32 + g*8];
      acc[0][0] = __builtin_amdgcn_mfma_f32_16x16x32_bf16(a0, b0, acc[0][0], 0,0,0);
      acc[0][1] = __builtin_amdgcn_mfma_f32_16x16x32_bf16(a0, b1, acc[0][1], 0,0,0);
      acc[1][0] = __builtin_amdgcn_mfma_f32_16x16x32_bf16(a1, b0, acc[1][0], 0,0,0);
      acc[1][1] = __builtin_amdgcn_mfma_f32_16x16x32_bf16(a1, b1, acc[1][1], 0,0,0);
    }
    __syncthreads();
  }

  const int Cout = gridDim.y*64;
  #pragma unroll
  for (int fr = 0; fr < 2; fr++){
    #pragma unroll
    for (int fc = 0; fc < 2; fc++){
      const int o = ob + wR*32 + fr*16 + 4*g;
      const int n = nb + wC*32 + fc*16 + l15;
      const f32x4 v = acc[fr][fc];
      if (EPIM == 0){
        if (ob < 1024){
          const int qk = o >> 9, h = (o >> 6) & 7, d = o & 63;
          ushort4 pk = make_ushort4(f2bf(v[0]), f2bf(v[1]), f2bf(v[2]), f2bf(v[3]));
          ushort* dst = qt + ((((size_t)qk*4 + b)*8 + h)*NPIX + n)*64 + d;
          *(ushort4*)dst = pk;
        } else {
          const int c = o - 1024;
          #pragma unroll
          for (int r = 0; r < 4; r++)
            v16[((size_t)b*512 + c + r)*NPIX + n] = f2bf(v[r]);
        }
      } else {
        #pragma unroll
        for (int r = 0; r < 4; r++){
          float val = v[r];
          if (BIAS) val += bias[o + r];
          if (BN2F) val = val*s2[o+r] + t2[o+r];
          const size_t row = ((size_t)b*Cout + o + r)*NPIX + n;
          if (EPIM == 1){ ((float*)out)[row] = val + res[row]; }
          else if (EPIM == 2){ ((float*)out)[row] = val; }
          else {
            val += res[row];
            if (*flag) ((float*)out)[row] = val;
            else       ((ushort*)out)[row] = f2bf(val);
          }
        }
      }
    }
  }
}

// ---------------- MFMA differential attention ----------------
// grid (16 q-tiles, 8 h, 4 b), 256 thr (4 waves x 16 q each).
// S^T = K·Q (swapped) so each lane holds P for fixed q; PV straight from regs.
__global__ __launch_bounds__(256) void attn_kernel(
    const ushort* __restrict__ QT,   // [2][4][8][1024][64]
    const ushort* __restrict__ V16,  // [4][512][1024]
    const float* __restrict__ Pf,
    ushort* __restrict__ att)        // [4][1024][512]
{
  const int t = threadIdx.x;
  const int lane = t & 63, w = t >> 6;
  const int l15 = lane & 15, g = lane >> 4;
  const int qt = blockIdx.x, h = blockIdx.y, b = blockIdx.z;
  const int qsub = qt*64 + w*16;
  const ushort* Qb = QT + (((size_t)(0*4 + b)*8 + h)*NPIX)*64;
  const ushort* Kb = QT + (((size_t)(1*4 + b)*8 + h)*NPIX)*64;
  const ushort* Vb = V16 + ((size_t)b*512 + h*64)*NPIX;

  s16x8 bq[2];
  #pragma unroll
  for (int hx = 0; hx < 2; hx++)
    bq[hx] = *(const s16x8*)&Qb[(size_t)(qsub + l15)*64 + 32*hx + 8*g];

  float e1 = 0.f, e2 = 0.f;
  #pragma unroll 8
  for (int i = 0; i < 32; i++){
    e1 += Pf[1442304 + h*32 + i] * Pf[1442560 + h*32 + i];
    e2 += Pf[1442816 + h*32 + i] * Pf[1443072 + h*32 + i];
  }
  const float lam = __expf(e1) - __expf(e2) + LAMBDA_INIT_F;

  const f32x4 z4 = {0.f,0.f,0.f,0.f};
  f32x4 o0[4] = {z4,z4,z4,z4};
  f32x4 o1[4] = {z4,z4,z4,z4};
  float z[2] = {0.f, 0.f};

  for (int mt = 0; mt < 32; mt++){
    const int m0 = mt*32;
    f32x4 s[2][2];
    #pragma unroll
    for (int hx = 0; hx < 2; hx++)
      #pragma unroll
      for (int fr = 0; fr < 2; fr++){
        const s16x8 ak = *(const s16x8*)&Kb[(size_t)(m0 + fr*16 + l15)*64 + 32*hx + 8*g];
        s[hx][fr] = __builtin_amdgcn_mfma_f32_16x16x32_bf16(ak, bq[hx], z4, 0,0,0);
      }
    s16x8 pa[2];
    #pragma unroll
    for (int hx = 0; hx < 2; hx++){
      ushort tmp[8];
      #pragma unroll
      for (int fr = 0; fr < 2; fr++)
        #pragma unroll
        for (int r = 0; r < 4; r++){
          const float ev = __expf(s[hx][fr][r] * ATT_SCALE);
          z[hx] += ev;
          tmp[fr*4 + r] = f2bf(ev);      // slot j: fr=j>>2, r=j&3  (kappa_PV)
        }
      pa[hx] = *(s16x8*)tmp;
    }
    #pragma unroll
    for (int dc = 0; dc < 4; dc++){
      const ushort* vp = &Vb[(size_t)(dc*16 + l15)*NPIX + m0 + 4*g];
      const ushort4 lo = *(const ushort4*)vp;
      const ushort4 hi = *(const ushort4*)(vp + 16);
      s16x8 bv;
      bv[0]=(short)lo.x; bv[1]=(short)lo.y; bv[2]=(short)lo.z; bv[3]=(short)lo.w;
      bv[4]=(short)hi.x; bv[5]=(short)hi.y; bv[6]=(short)hi.z; bv[7]=(short)hi.w;
      o0[dc] = __builtin_amdgcn_mfma_f32_16x16x32_bf16(pa[0], bv, o0[dc], 0,0,0);
      o1[dc] = __builtin_amdgcn_mfma_f32_16x16x32_bf16(pa[1], bv, o1[dc], 0,0,0);
    }
  }

  // Z: reduce over g-groups (lanes ^16, ^32); every lane gets Z[q=l15]
  #pragma unroll
  for (int hx = 0; hx < 2; hx++){
    z[hx] += __shfl_xor(z[hx], 16);
    z[hx] += __shfl_xor(z[hx], 32);
  }
  float zi0[4], zi1[4];
  #pragma unroll
  for (int r = 0; r < 4; r++){
    zi0[r] = 1.f / __shfl(z[0], 4*g + r);
    zi1[r] = 1.f / __shfl(z[1], 4*g + r);
  }
  float val[4][4];
  float ss[4] = {0.f,0.f,0.f,0.f};
  #pragma unroll
  for (int dc = 0; dc < 4; dc++)
    #pragma unroll
    for (int r = 0; r < 4; r++){
      const float vv = o0[dc][r]*zi0[r] - lam*o1[dc][r]*zi1[r];
      val[dc][r] = vv; ss[r] += vv*vv;
    }
  #pragma unroll
  for (int r = 0; r < 4; r++){
    ss[r] += __shfl_xor(ss[r], 1);
    ss[r] += __shfl_xor(ss[r], 2);
    ss[r] += __shfl_xor(ss[r], 4);
    ss[r] += __shfl_xor(ss[r], 8);
  }
  float rinv[4];
  #pragma unroll
  for (int r = 0; r < 4; r++) rinv[r] = ONE_M_LI * rsqrtf(ss[r]*(1.f/64.f) + EPSF);
  #pragma unroll
  for (int dc = 0; dc < 4; dc++){
    const float rs = Pf[1443328 + dc*16 + l15];
    #pragma unroll
    for (int r = 0; r < 4; r++){
      const int n = qsub + 4*g + r;
      att[((size_t)b*NPIX + n)*512 + h*64 + dc*16 + l15] = f2bf(val[dc][r]*rinv[r]*rs);
    }
  }
}

// ---------------- depthwise 3x3 (768 ch) ----------------
__global__ void dwconv3_kernel(const float* __restrict__ in, const float* __restrict__ w,
                               float* __restrict__ out){
  const int gIdx = blockIdx.x*256 + threadIdx.x;
  const int x = gIdx & 31, y = (gIdx >> 5) & 31;
  const int plane = gIdx >> 10;
  const int c = plane % 768;
  const float* ip = in + (size_t)plane*NPIX;
  float s = 0.f;
  #pragma unroll
  for (int ky = 0; ky < 3; ky++){
    const int yy = y + ky - 1;
    if (yy < 0 || yy > 31) continue;
    #pragma unroll
    for (int kx = 0; kx < 3; kx++){
      const int xx = x + kx - 1;
      if (xx < 0 || xx > 31) continue;
      s = fmaf(ip[yy*32+xx], w[c*9 + ky*3 + kx], s);
    }
  }
  out[gIdx] = s;
}

// ---------------- L2-normalize rows over n (CHA q,k) ----------------
__global__ __launch_bounds__(256) void l2norm_kernel(float* __restrict__ x){
  const int r = blockIdx.x;
  const int b = r >> 9, c = r & 511;
  float* p = x + ((size_t)b*768 + c)*NPIX;
  const int t = threadIdx.x;
  float4 v = ((float4*)p)[t];
  float s = v.x*v.x + v.y*v.y + v.z*v.z + v.w*v.w;
  for (int off = 32; off; off >>= 1) s += __shfl_down(s, off);
  __shared__ float wsum[4];
  if ((t & 63) == 0) wsum[t >> 6] = s;
  __syncthreads();
  const float tot = wsum[0] + wsum[1] + wsum[2] + wsum[3];
  const float inv = 1.f / fmaxf(sqrtf(tot), 1e-12f);
  ((float4*)p)[t] = make_float4(v.x*inv, v.y*inv, v.z*inv, v.w*inv);
}

// ---------------- CHA partial scores ----------------
__global__ __launch_bounds__(256) void cha_scores_kernel(const float* __restrict__ qk,
                                                         float* __restrict__ spart){
  __shared__ float qs[32][129];
  __shared__ float ks[32][129];
  const int t = threadIdx.x;
  const int nb = blockIdx.x*128;
  const int bh = blockIdx.y, b = bh >> 3, h = bh & 7;
  const size_t qbase = ((size_t)b*768 + h*32)*NPIX + nb;
  const size_t kbase = qbase + (size_t)256*NPIX;
  { const int c = t >> 3, n0 = (t & 7)*16;
    #pragma unroll
    for (int j = 0; j < 16; j++){
      qs[c][n0+j] = qk[qbase + (size_t)c*NPIX + n0 + j];
      ks[c][n0+j] = qk[kbase + (size_t)c*NPIX + n0 + j];
    } }
  __syncthreads();
  const int c = t & 31, dg = t >> 5;
  float acc[4] = {};
  for (int nn = 0; nn < 128; nn++){
    const float qv = qs[c][nn];
    #pragma unroll
    for (int j = 0; j < 4; j++) acc[j] = fmaf(qv, ks[dg*4+j][nn], acc[j]);
  }
  float* sp = spart + ((size_t)bh*8 + blockIdx.x)*1024 + c*32 + dg*4;
  #pragma unroll
  for (int j = 0; j < 4; j++) sp[j] = acc[j];
}

// ---------------- CHA softmax ----------------
__global__ void cha_softmax_kernel(const float* __restrict__ spart,
                                   const float* __restrict__ temp, float* __restrict__ P){
  __shared__ float Ss[32][33];
  const int t = threadIdx.x;
  const int bh = blockIdx.x, h = bh & 7;
  const float tf = temp[h];
  for (int p = t*4; p < t*4+4; p++){
    float s = 0.f;
    for (int ch = 0; ch < 8; ch++) s += spart[((size_t)bh*8 + ch)*1024 + p];
    Ss[p >> 5][p & 31] = s * tf;
  }
  __syncthreads();
  if (t < 32){
    float mx = -1e30f;
    for (int d = 0; d < 32; d++) mx = fmaxf(mx, Ss[t][d]);
    float sum = 0.f;
    for (int d = 0; d < 32; d++){ const float e = __expf(Ss[t][d]-mx); Ss[t][d] = e; sum += e; }
    const float inv = 1.f/sum;
    for (int d = 0; d < 32; d++) P[(size_t)bh*1024 + t*32 + d] = Ss[t][d]*inv;
  }
}

// ---------------- CHA PV ----------------
__global__ __launch_bounds__(256) void cha_pv_kernel(const float* __restrict__ P,
                                                     const float* __restrict__ qkv,
                                                     float* __restrict__ out){
  __shared__ float Ps[32][33];
  const int t = threadIdx.x;
  const int bh = blockIdx.y, b = bh >> 3, h = bh & 7;
  const int nb = blockIdx.x*64;
  for (int p = t; p < 1024; p += 256) Ps[p >> 5][p & 31] = P[(size_t)bh*1024 + p];
  __syncthreads();
  const int n = nb + (t & 63);
  const int cg = t >> 6;
  const size_t vbase = ((size_t)b*768 + 512 + h*32)*NPIX + n;
  float acc[8] = {};
  for (int d = 0; d < 32; d++){
    const float v = qkv[vbase + (size_t)d*NPIX];
    #pragma unroll
    for (int j = 0; j < 8; j++) acc[j] = fmaf(Ps[cg*8+j][d], v, acc[j]);
  }
  const size_t obase = ((size_t)b*256 + h*32 + cg*8)*NPIX + n;
  #pragma unroll
  for (int j = 0; j < 8; j++) out[obase + (size_t)j*NPIX] = acc[j];
}

// ---------------- FFN grouped 3x3 + bias + relu6 ----------------
__global__ void gconv3_kernel(const float* __restrict__ in, const float* __restrict__ w,
                              const float* __restrict__ bias, float* __restrict__ out){
  const int gIdx = blockIdx.x*256 + threadIdx.x;
  const int x = gIdx & 31, y = (gIdx >> 5) & 31;
  const int plane = gIdx >> 10;
  const int o = plane & 511, b = plane >> 9;
  const float* ip = in + ((size_t)b*512 + (o & ~1))*NPIX;
  float s = bias[o];
  #pragma unroll
  for (int ci = 0; ci < 2; ci++){
    #pragma unroll
    for (int ky = 0; ky < 3; ky++){
      const int yy = y + ky - 1;
      if (yy < 0 || yy > 31) continue;
      #pragma unroll
      for (int kx = 0; kx < 3; kx++){
        const int xx = x + kx - 1;
        if (xx < 0 || xx > 31) continue;
        s = fmaf(ip[(size_t)ci*NPIX + yy*32+xx], w[o*18 + ci*9 + ky*3 + kx], s);
      }
    }
  }
  out[gIdx] = fminf(fmaxf(s, 0.f), 6.f);
}

extern "C" void kernel_launch(void* const* d_in, const int* in_sizes, int n_in,
                              void* d_out, int out_size, void* d_ws, size_t ws_size,
                              hipStream_t stream)
{
  (void)in_sizes; (void)n_in; (void)out_size; (void)ws_size;

  float* ws   = (float*)d_ws;
  float* P    = ws;
  float* xbuf = P;                                // residual (packed x)
  ushort* Wbf = (ushort*)(ws + OFF_WBF);
  ushort* QT  = (ushort*)(ws + OFF_QT);
  ushort* V16 = (ushort*)(ws + OFF_V16);
  ushort* att = (ushort*)(ws + OFF_ATT);
  float* chaout = ws + OFF_ATT;                   // att dead by then
  float* buf1 = ws + OFF_BUF1;
  float* buf2 = ws + OFF_BUF2;
  float* spart= ws + OFF_SPART;
  float* pbuf = ws + OFF_PBUF;
  float* stats= ws + OFF_STATS;
  float* eff  = ws + OFF_EFF;
  int*  flag  = (int*)(ws + OFF_FLAG);

  const float* b1f = P + 1976648;
  const float* b3f = P + 2120008;
  const float* wdw = P + 1771592;
  const float* w2f = P + 1979208;
  const float* b2f_ = P + 1988424;
  const float* temp = P + 1574976;

  detect_kernel<<<1, 256, 0, stream>>>(d_in[0], flag);
  PackArgs pa;
  for (int i = 0; i < 34; i++) pa.p[i] = d_in[i];
  pack_kernel<<<8283, 256, 0, stream>>>(pa, flag, P);
  wpack_kernel<<<4096, 256, 0, stream>>>(P, Wbf);
  prep_kernel<<<1, 256, 0, stream>>>(P, eff);

  // ---- CDA ----
  ln_stats_kernel<<<64, 256, 0, stream>>>(xbuf, stats, stats+4096);
  gemm_kernel<0,0,false,false><<<dim3(16,24,4), 256, 0, stream>>>(
      xbuf, nullptr, Wbf, nullptr, stats, stats+4096, eff, eff+256,
      nullptr, nullptr, nullptr, nullptr, QT, V16, 256, nullptr);
  attn_kernel<<<dim3(16,8,4), 256, 0, stream>>>(QT, V16, P, att);
  gemm_kernel<2,1,false,false><<<dim3(16,4,4), 256, 0, stream>>>(
      nullptr, att, Wbf+589824, nullptr, nullptr, nullptr, nullptr, nullptr,
      nullptr, nullptr, xbuf, xbuf, nullptr, nullptr, 512, nullptr);

  // ---- CHA ----
  ln_stats_kernel<<<64, 256, 0, stream>>>(xbuf, stats+8192, stats+12288);
  gemm_kernel<0,2,false,false><<<dim3(16,12,4), 256, 0, stream>>>(
      xbuf, nullptr, Wbf+393216, nullptr, stats+8192, stats+12288, eff+512, eff+768,
      nullptr, nullptr, nullptr, buf1, nullptr, nullptr, 256, nullptr);
  dwconv3_kernel<<<12288, 256, 0, stream>>>(buf1, wdw, buf2);
  l2norm_kernel<<<2048, 256, 0, stream>>>(buf2);
  cha_scores_kernel<<<dim3(8,32), 256, 0, stream>>>(buf2, spart);
  cha_softmax_kernel<<<32, 256, 0, stream>>>(spart, temp, pbuf);
  cha_pv_kernel<<<dim3(16,32), 256, 0, stream>>>(pbuf, buf2, chaout);
  gemm_kernel<1,1,false,false><<<dim3(16,4,4), 256, 0, stream>>>(
      chaout, nullptr, Wbf+720896, nullptr, nullptr, nullptr, nullptr, nullptr,
      nullptr, nullptr, xbuf, xbuf, nullptr, nullptr, 256, nullptr);

  // ---- FFN ----
  ln_stats_kernel<<<64, 256, 0, stream>>>(xbuf, stats+16384, stats+20480);
  gemm_kernel<0,2,true,true><<<dim3(16,8,4), 256, 0, stream>>>(
      xbuf, nullptr, Wbf+786432, b1f, stats+16384, stats+20480, eff+1024, eff+1280,
      eff+1536, eff+2048, nullptr, buf1, nullptr, nullptr, 256, nullptr);
  gconv3_kernel<<<8192, 256, 0, stream>>>(buf1, w2f, b2f_, buf2);
  gemm_kernel<1,3,true,false><<<dim3(16,4,4), 256, 0, stream>>>(
      buf2, nullptr, Wbf+917504, b3f, nullptr, nullptr, nullptr, nullptr,
      nullptr, nullptr, xbuf, d_out, nullptr, nullptr, 512, flag);
}

// Round 5
// 358.602 us; speedup vs baseline: 2.7599x; 1.0410x over previous
//
#include <hip/hip_runtime.h>
#include <hip/hip_bf16.h>

typedef __hip_bfloat16 bf16;
typedef __attribute__((ext_vector_type(8))) short s16x8;
typedef __attribute__((ext_vector_type(4))) float f32x4;

#define DEV __device__ __forceinline__

DEV float b2f(bf16 v){ return __bfloat162float(v); }
DEV ushort f2bf(float f){ bf16 h = __float2bfloat16(f); return *reinterpret_cast<ushort*>(&h); }

constexpr int NPIX = 1024;
constexpr float EPSF = 1e-5f;
constexpr float LAMBDA_INIT_F = 0.3555090675909693f;   // 0.8 - 0.6*exp(-0.3)
constexpr float ONE_M_LI     = 0.6444909324090307f;
constexpr float ATT_SCALE    = 0.17677669529663687f;   // 32^-0.5

// workspace offsets (in floats)
constexpr size_t OFF_WBF   = 2120448;   // bf16 weights, 1048576 elems
constexpr size_t OFF_QT    = 2644736;   // QT/KT bf16 [2][4][8][1024][64]
constexpr size_t OFF_V16   = 4741888;   // V bf16 [4][512][1024]
constexpr size_t OFF_ATT   = 5790464;   // att bf16 [4][1024][512]; later chaout f32
constexpr size_t OFF_BUF1  = 6839040;   // f32 [4][768][1024] qkv / ffn1
constexpr size_t OFF_BUF2  = 9984768;   // f32 dw / gconv out
constexpr size_t OFF_SPART = 13130496;
constexpr size_t OFF_STATS = 13425408;  // mu1,r1,mu2,r2,mu3,r3 (6*4096)
constexpr size_t OFF_EFF   = 13449984;  // folded params (2560) + lam(8)
constexpr size_t OFF_FLAG  = 13452608;

struct PackArgs { const void* p[34]; };

// ---------------- dtype detect ----------------
__global__ __launch_bounds__(256) void detect_kernel(const void* __restrict__ x, int* __restrict__ flag){
  __shared__ int sh;
  if (threadIdx.x == 0) sh = 0;
  __syncthreads();
  const bf16* h = (const bf16*)x;
  int local = 0;
  for (int i = threadIdx.x; i < 4096; i += 256){
    float v = b2f(h[i]);
    if (!(fabsf(v) <= 1e6f)) local = 1;
  }
  if (local) atomicOr(&sh, 1);
  __syncthreads();
  if (threadIdx.x == 0) *flag = sh;
}

DEV float rdin(const PackArgs& a, int i, int idx, int flag){
  return flag ? ((const float*)a.p[i])[idx] : b2f(((const bf16*)a.p[i])[idx]);
}

// ---------------- prep_all: pack(8283) + wpack(1024) + prep(1) ----------------
__global__ __launch_bounds__(256) void prep_all_kernel(PackArgs args, const int* __restrict__ flagp,
    float* __restrict__ P, ushort* __restrict__ W, float* __restrict__ eff){
  const int t = threadIdx.x;
  const int blk = blockIdx.x;
  const int flag = *flagp;
  if (blk < 8283){
    constexpr int NIN = 34;
    constexpr int off[NIN+1] = {0,1048576,1048832,1049088,1180160,1311232,1442304,1442560,
      1442816,1443072,1443328,1443392,1574464,1574720,1574976,1574984,1771592,1778504,
      1844040,1844296,1844552,1844808,1845064,1845320,1845576,1976648,1977160,1977672,
      1978184,1978696,1979208,1988424,1988936,2120008,2120264};
    const int g = blk*256 + t;
    if (g >= off[NIN]) return;
    int idx = 0;
    #pragma unroll
    for (int k = 1; k < NIN; k++) idx = (g >= off[k]) ? k : idx;
    P[g] = rdin(args, idx, g - off[idx], flag);
  } else if (blk < 9307){
    // weight bf16 pack straight from inputs
    const int g = (blk - 8283)*1024 + t*4;     // < 1048576, 4 elems, never straddles
    int src, loc;
    if      (g <  131072){ src = 3;  loc = g; }
    else if (g <  262144){ src = 4;  loc = g - 131072; }
    else if (g <  393216){ src = 5;  loc = g - 262144; }
    else if (g <  589824){ src = 15; loc = g - 393216; }
    else if (g <  720896){ src = 11; loc = g - 589824; }
    else if (g <  786432){ src = 17; loc = g - 720896; }
    else if (g <  917504){ src = 24; loc = g - 786432; }
    else                 { src = 32; loc = g - 917504; }
    ushort4 o;
    if (flag){
      const float4 v = *(const float4*)((const float*)args.p[src] + loc);
      o = make_ushort4(f2bf(v.x), f2bf(v.y), f2bf(v.z), f2bf(v.w));
    } else {
      o = *(const ushort4*)((const ushort*)args.p[src] + loc);
    }
    *(ushort4*)&W[g] = o;
  } else {
    // folded params + lambda
    eff[t]      = rdin(args,1,t,flag);  eff[256+t] = rdin(args,2,t,flag);
    eff[512+t]  = rdin(args,12,t,flag); eff[768+t] = rdin(args,13,t,flag);
    const float s1 = rdin(args,20,t,flag) * rsqrtf(rdin(args,23,t,flag) + EPSF);
    eff[1024+t] = rdin(args,18,t,flag) * s1;
    eff[1280+t] = (rdin(args,19,t,flag) - rdin(args,22,t,flag)) * s1 + rdin(args,21,t,flag);
    for (int c = t; c < 512; c += 256){
      const float sc = rdin(args,26,c,flag) * rsqrtf(rdin(args,29,c,flag) + EPSF);
      eff[1536+c] = sc;
      eff[2048+c] = rdin(args,27,c,flag) - rdin(args,28,c,flag)*sc;
    }
    if (t < 8){
      float e1 = 0.f, e2 = 0.f;
      for (int i = 0; i < 32; i++){
        e1 += rdin(args,6,t*32+i,flag) * rdin(args,7,t*32+i,flag);
        e2 += rdin(args,8,t*32+i,flag) * rdin(args,9,t*32+i,flag);
      }
      eff[2560+t] = __expf(e1) - __expf(e2) + LAMBDA_INIT_F;
    }
  }
}

// ---------------- LN stats: mu, rstd per (b, n) ----------------
__global__ __launch_bounds__(256) void ln_stats_kernel(const float* __restrict__ x,
    float* __restrict__ mu, float* __restrict__ rstd){
  __shared__ float ps[16][64], ps2[16][64];
  const int t = threadIdx.x;
  const int b = blockIdx.x >> 4, n0 = (blockIdx.x & 15)*64;
  const int tn = t & 15, tc = t >> 4;
  float4 s = {0,0,0,0}, q = {0,0,0,0};
  #pragma unroll
  for (int i = 0; i < 16; i++){
    const int c = tc*16 + i;
    const float4 v = *(const float4*)&x[((size_t)b*256 + c)*NPIX + n0 + tn*4];
    s.x += v.x; s.y += v.y; s.z += v.z; s.w += v.w;
    q.x += v.x*v.x; q.y += v.y*v.y; q.z += v.z*v.z; q.w += v.w*v.w;
  }
  ps[tc][tn*4+0]=s.x; ps[tc][tn*4+1]=s.y; ps[tc][tn*4+2]=s.z; ps[tc][tn*4+3]=s.w;
  ps2[tc][tn*4+0]=q.x; ps2[tc][tn*4+1]=q.y; ps2[tc][tn*4+2]=q.z; ps2[tc][tn*4+3]=q.w;
  __syncthreads();
  if (t < 64){
    float a = 0.f, qq = 0.f;
    #pragma unroll
    for (int j = 0; j < 16; j++){ a += ps[j][t]; qq += ps2[j][t]; }
    const float m = a * (1.f/256.f);
    float var = qq * (1.f/256.f) - m*m; var = fmaxf(var, 0.f);
    mu[(size_t)b*NPIX + n0 + t] = m;
    rstd[(size_t)b*NPIX + n0 + t] = rsqrtf(var + EPSF);
  }
}

// ---------------- unified MFMA GEMM ----------------
template<int INM, int EPIM, bool BIAS, bool BN2F>
__global__ __launch_bounds__(256) void gemm_kernel(
    const float* __restrict__ Xf, const ushort* __restrict__ Xb, const ushort* __restrict__ W,
    const float* __restrict__ bias, const float* __restrict__ mu, const float* __restrict__ rstd,
    const float* __restrict__ effw, const float* __restrict__ effb,
    const float* __restrict__ s2, const float* __restrict__ t2,
    const float* __restrict__ res, void* __restrict__ out,
    ushort* __restrict__ qt, ushort* __restrict__ v16,
    int Cin, const int* __restrict__ flag)
{
  __shared__ ushort Xt[64][72];
  const int t = threadIdx.x;
  const int nb = blockIdx.x*64, ob = blockIdx.y*64, b = blockIdx.z;
  const int lane = t & 63, w = t >> 6;
  const int wR = w >> 1, wC = w & 1;
  const int l15 = lane & 15, g = lane >> 4;
  const int tn = t & 63, tc4 = t >> 6;
  const f32x4 z4 = {0.f,0.f,0.f,0.f};
  f32x4 acc[2][2] = {{z4,z4},{z4,z4}};

  for (int kb = 0; kb < Cin; kb += 64){
    if (INM == 2){
      const ushort* src = Xb + ((size_t)b*NPIX + nb + tn)*Cin + kb + tc4*16;
      *(uint4*)&Xt[tn][tc4*16]   = *(const uint4*)src;
      *(uint4*)&Xt[tn][tc4*16+8] = *(const uint4*)(src+8);
    } else {
      float m_ = 0.f, r_ = 1.f;
      if (INM == 0){ m_ = mu[(size_t)b*NPIX + nb + tn]; r_ = rstd[(size_t)b*NPIX + nb + tn]; }
      ushort tmp[16];
      #pragma unroll
      for (int i = 0; i < 16; i++){
        const int c = kb + tc4*16 + i;
        float v = Xf[((size_t)b*Cin + c)*NPIX + nb + tn];
        if (INM == 0) v = (v - m_)*r_*effw[c] + effb[c];
        tmp[i] = f2bf(v);
      }
      *(uint4*)&Xt[tn][tc4*16]   = *(uint4*)&tmp[0];
      *(uint4*)&Xt[tn][tc4*16+8] = *(uint4*)&tmp[8];
    }
    __syncthreads();
    #pragma unroll
    for (int ks = 0; ks < 2; ks++){
      const s16x8 a0 = *(const s16x8*)&W[(size_t)(ob + wR*32 + l15)*Cin + kb + ks*32 + g*8];
      const s16x8 a1 = *(const s16x8*)&W[(size_t)(ob + wR*32 + 16 + l15)*Cin + kb + ks*32 + g*8];
      const s16x8 b0 = *(const s16x8*)&Xt[wC*32 + l15][ks*32 + g*8];
      const s16x8 b1 = *(const s16x8*)&Xt[wC*32 + 16 + l15][ks*32 + g*8];
      acc[0][0] = __builtin_amdgcn_mfma_f32_16x16x32_bf16(a0, b0, acc[0][0], 0,0,0);
      acc[0][1] = __builtin_amdgcn_mfma_f32_16x16x32_bf16(a0, b1, acc[0][1], 0,0,0);
      acc[1][0] = __builtin_amdgcn_mfma_f32_16x16x32_bf16(a1, b0, acc[1][0], 0,0,0);
      acc[1][1] = __builtin_amdgcn_mfma_f32_16x16x32_bf16(a1, b1, acc[1][1], 0,0,0);
    }
    __syncthreads();
  }

  const int Cout = gridDim.y*64;
  #pragma unroll
  for (int fr = 0; fr < 2; fr++){
    #pragma unroll
    for (int fc = 0; fc < 2; fc++){
      const int o = ob + wR*32 + fr*16 + 4*g;
      const int n = nb + wC*32 + fc*16 + l15;
      const f32x4 v = acc[fr][fc];
      if (EPIM == 0){
        if (ob < 1024){
          const int qk = o >> 9, h = (o >> 6) & 7, d = o & 63;
          ushort4 pk = make_ushort4(f2bf(v[0]), f2bf(v[1]), f2bf(v[2]), f2bf(v[3]));
          ushort* dst = qt + ((((size_t)qk*4 + b)*8 + h)*NPIX + n)*64 + d;
          *(ushort4*)dst = pk;
        } else {
          const int c = o - 1024;
          #pragma unroll
          for (int r = 0; r < 4; r++)
            v16[((size_t)b*512 + c + r)*NPIX + n] = f2bf(v[r]);
        }
      } else {
        #pragma unroll
        for (int r = 0; r < 4; r++){
          float val = v[r];
          if (BIAS) val += bias[o + r];
          if (BN2F) val = val*s2[o+r] + t2[o+r];
          const size_t row = ((size_t)b*Cout + o + r)*NPIX + n;
          if (EPIM == 1){ ((float*)out)[row] = val + res[row]; }
          else if (EPIM == 2){ ((float*)out)[row] = val; }
          else {
            val += res[row];
            if (*flag) ((float*)out)[row] = val;
            else       ((ushort*)out)[row] = f2bf(val);
          }
        }
      }
    }
  }
}

// ---------------- MFMA differential attention, ILP-2 over m ----------------
// grid (16 q-tiles, 8 h, 4 b), 256 thr. Stream A: m in [0,512), B: [512,1024).
__global__ __launch_bounds__(256) void attn_kernel(
    const ushort* __restrict__ QT, const ushort* __restrict__ V16,
    const float* __restrict__ Pf, const float* __restrict__ lamArr,
    ushort* __restrict__ att)
{
  const int t = threadIdx.x;
  const int lane = t & 63, w = t >> 6;
  const int l15 = lane & 15, g = lane >> 4;
  const int qt = blockIdx.x, h = blockIdx.y, b = blockIdx.z;
  const int qsub = qt*64 + w*16;
  const ushort* Qb = QT + (((size_t)b*8 + h)*NPIX)*64;
  const ushort* Kb = QT + (((size_t)(4 + b)*8 + h)*NPIX)*64;
  const ushort* Vb = V16 + ((size_t)b*512 + h*64)*NPIX;

  s16x8 bq[2];
  #pragma unroll
  for (int hx = 0; hx < 2; hx++)
    bq[hx] = *(const s16x8*)&Qb[(size_t)(qsub + l15)*64 + 32*hx + 8*g];
  const float lam = lamArr[h];

  const f32x4 z4 = {0.f,0.f,0.f,0.f};
  f32x4 oA0[4] = {z4,z4,z4,z4}, oA1[4] = {z4,z4,z4,z4};
  f32x4 oB0[4] = {z4,z4,z4,z4}, oB1[4] = {z4,z4,z4,z4};
  float zA[2] = {0.f,0.f}, zB[2] = {0.f,0.f};

  #pragma unroll 1
  for (int it = 0; it < 16; it++){
    const int mA = it*32, mB = it*32 + 512;
    s16x8 akA[2][2], akB[2][2];
    #pragma unroll
    for (int hx = 0; hx < 2; hx++)
      #pragma unroll
      for (int fr = 0; fr < 2; fr++){
        akA[hx][fr] = *(const s16x8*)&Kb[(size_t)(mA + fr*16 + l15)*64 + 32*hx + 8*g];
        akB[hx][fr] = *(const s16x8*)&Kb[(size_t)(mB + fr*16 + l15)*64 + 32*hx + 8*g];
      }
    s16x8 bvA[4], bvB[4];
    #pragma unroll
    for (int dc = 0; dc < 4; dc++){
      const ushort* vpA = &Vb[(size_t)(dc*16 + l15)*NPIX + mA + 4*g];
      const ushort* vpB = &Vb[(size_t)(dc*16 + l15)*NPIX + mB + 4*g];
      const ushort4 loA = *(const ushort4*)vpA; const ushort4 hiA = *(const ushort4*)(vpA + 16);
      const ushort4 loB = *(const ushort4*)vpB; const ushort4 hiB = *(const ushort4*)(vpB + 16);
      s16x8 a, c;
      a[0]=(short)loA.x; a[1]=(short)loA.y; a[2]=(short)loA.z; a[3]=(short)loA.w;
      a[4]=(short)hiA.x; a[5]=(short)hiA.y; a[6]=(short)hiA.z; a[7]=(short)hiA.w;
      c[0]=(short)loB.x; c[1]=(short)loB.y; c[2]=(short)loB.z; c[3]=(short)loB.w;
      c[4]=(short)hiB.x; c[5]=(short)hiB.y; c[6]=(short)hiB.z; c[7]=(short)hiB.w;
      bvA[dc] = a; bvB[dc] = c;
    }
    f32x4 sA[2][2], sB[2][2];
    #pragma unroll
    for (int hx = 0; hx < 2; hx++)
      #pragma unroll
      for (int fr = 0; fr < 2; fr++){
        sA[hx][fr] = __builtin_amdgcn_mfma_f32_16x16x32_bf16(akA[hx][fr], bq[hx], z4, 0,0,0);
        sB[hx][fr] = __builtin_amdgcn_mfma_f32_16x16x32_bf16(akB[hx][fr], bq[hx], z4, 0,0,0);
      }
    s16x8 paA[2], paB[2];
    #pragma unroll
    for (int hx = 0; hx < 2; hx++){
      ushort ta[8], tb[8];
      #pragma unroll
      for (int fr = 0; fr < 2; fr++)
        #pragma unroll
        for (int r = 0; r < 4; r++){
          const float eA = __expf(sA[hx][fr][r] * ATT_SCALE);
          const float eB = __expf(sB[hx][fr][r] * ATT_SCALE);
          zA[hx] += eA; zB[hx] += eB;
          ta[fr*4 + r] = f2bf(eA); tb[fr*4 + r] = f2bf(eB);
        }
      paA[hx] = *(s16x8*)ta; paB[hx] = *(s16x8*)tb;
    }
    __builtin_amdgcn_s_setprio(1);
    #pragma unroll
    for (int dc = 0; dc < 4; dc++){
      oA0[dc] = __builtin_amdgcn_mfma_f32_16x16x32_bf16(paA[0], bvA[dc], oA0[dc], 0,0,0);
      oB0[dc] = __builtin_amdgcn_mfma_f32_16x16x32_bf16(paB[0], bvB[dc], oB0[dc], 0,0,0);
      oA1[dc] = __builtin_amdgcn_mfma_f32_16x16x32_bf16(paA[1], bvA[dc], oA1[dc], 0,0,0);
      oB1[dc] = __builtin_amdgcn_mfma_f32_16x16x32_bf16(paB[1], bvB[dc], oB1[dc], 0,0,0);
    }
    __builtin_amdgcn_s_setprio(0);
  }

  float z[2] = {zA[0] + zB[0], zA[1] + zB[1]};
  #pragma unroll
  for (int hx = 0; hx < 2; hx++){
    z[hx] += __shfl_xor(z[hx], 16);
    z[hx] += __shfl_xor(z[hx], 32);
  }
  float zi0[4], zi1[4];
  #pragma unroll
  for (int r = 0; r < 4; r++){
    zi0[r] = 1.f / __shfl(z[0], 4*g + r);
    zi1[r] = 1.f / __shfl(z[1], 4*g + r);
  }
  float val[4][4];
  float ss[4] = {0.f,0.f,0.f,0.f};
  #pragma unroll
  for (int dc = 0; dc < 4; dc++)
    #pragma unroll
    for (int r = 0; r < 4; r++){
      const float vv = (oA0[dc][r]+oB0[dc][r])*zi0[r] - lam*(oA1[dc][r]+oB1[dc][r])*zi1[r];
      val[dc][r] = vv; ss[r] += vv*vv;
    }
  #pragma unroll
  for (int r = 0; r < 4; r++){
    ss[r] += __shfl_xor(ss[r], 1);
    ss[r] += __shfl_xor(ss[r], 2);
    ss[r] += __shfl_xor(ss[r], 4);
    ss[r] += __shfl_xor(ss[r], 8);
  }
  float rinv[4];
  #pragma unroll
  for (int r = 0; r < 4; r++) rinv[r] = ONE_M_LI * rsqrtf(ss[r]*(1.f/64.f) + EPSF);
  #pragma unroll
  for (int dc = 0; dc < 4; dc++){
    const float rs = Pf[1443328 + dc*16 + l15];
    #pragma unroll
    for (int r = 0; r < 4; r++){
      const int n = qsub + 4*g + r;
      att[((size_t)b*NPIX + n)*512 + h*64 + dc*16 + l15] = f2bf(val[dc][r]*rinv[r]*rs);
    }
  }
}

// ---------------- fused depthwise 3x3 + L2-norm (block = plane) ----------------
__global__ __launch_bounds__(256) void dwl2_kernel(const float* __restrict__ in,
    const float* __restrict__ wdw, float* __restrict__ out){
  __shared__ float tile[1024];
  __shared__ float wsum[4];
  const int p = blockIdx.x;                 // b*768 + c
  const int c = p % 768;
  const int t = threadIdx.x;
  const float* ip = in + (size_t)p*1024;
  *(float4*)&tile[t*4] = *(const float4*)&ip[t*4];
  float wv[9];
  #pragma unroll
  for (int i = 0; i < 9; i++) wv[i] = wdw[c*9+i];
  __syncthreads();
  float o[4]; float ssq = 0.f;
  #pragma unroll
  for (int j = 0; j < 4; j++){
    const int px = t*4 + j, x = px & 31, y = px >> 5;
    float s = 0.f;
    #pragma unroll
    for (int ky = 0; ky < 3; ky++){
      const int yy = y + ky - 1;
      if (yy < 0 || yy > 31) continue;
      #pragma unroll
      for (int kx = 0; kx < 3; kx++){
        const int xx = x + kx - 1;
        if (xx < 0 || xx > 31) continue;
        s = fmaf(tile[yy*32+xx], wv[ky*3+kx], s);
      }
    }
    o[j] = s; ssq += s*s;
  }
  for (int off = 32; off; off >>= 1) ssq += __shfl_down(ssq, off);
  if ((t & 63) == 0) wsum[t >> 6] = ssq;
  __syncthreads();
  float inv = 1.f;
  if (c < 512){
    const float tot = wsum[0]+wsum[1]+wsum[2]+wsum[3];
    inv = 1.f / fmaxf(sqrtf(tot), 1e-12f);
  }
  *(float4*)&out[(size_t)p*1024 + t*4] = make_float4(o[0]*inv, o[1]*inv, o[2]*inv, o[3]*inv);
}

// ---------------- CHA partial scores ----------------
__global__ __launch_bounds__(256) void cha_scores_kernel(const float* __restrict__ qk,
                                                         float* __restrict__ spart){
  __shared__ float qs[32][129];
  __shared__ float ks[32][129];
  const int t = threadIdx.x;
  const int nb = blockIdx.x*128;
  const int bh = blockIdx.y, b = bh >> 3, h = bh & 7;
  const size_t qbase = ((size_t)b*768 + h*32)*NPIX + nb;
  const size_t kbase = qbase + (size_t)256*NPIX;
  { const int c = t >> 3, n0 = (t & 7)*16;
    #pragma unroll
    for (int j = 0; j < 16; j++){
      qs[c][n0+j] = qk[qbase + (size_t)c*NPIX + n0 + j];
      ks[c][n0+j] = qk[kbase + (size_t)c*NPIX + n0 + j];
    } }
  __syncthreads();
  const int c = t & 31, dg = t >> 5;
  float acc[4] = {};
  for (int nn = 0; nn < 128; nn++){
    const float qv = qs[c][nn];
    #pragma unroll
    for (int j = 0; j < 4; j++) acc[j] = fmaf(qv, ks[dg*4+j][nn], acc[j]);
  }
  float* sp = spart + ((size_t)bh*8 + blockIdx.x)*1024 + c*32 + dg*4;
  #pragma unroll
  for (int j = 0; j < 4; j++) sp[j] = acc[j];
}

// ---------------- CHA softmax + PV (fused) ----------------
__global__ __launch_bounds__(256) void cha_pv_kernel(const float* __restrict__ spart,
    const float* __restrict__ tempP, const float* __restrict__ qkv, float* __restrict__ out){
  __shared__ float Ps[32][33];
  const int t = threadIdx.x;
  const int bh = blockIdx.y, b = bh >> 3, h = bh & 7;
  const int nb = blockIdx.x*64;
  const float tf = tempP[h];
  for (int p = t; p < 1024; p += 256){
    float s = 0.f;
    #pragma unroll
    for (int ch = 0; ch < 8; ch++) s += spart[((size_t)bh*8 + ch)*1024 + p];
    Ps[p >> 5][p & 31] = s * tf;
  }
  __syncthreads();
  if (t < 32){
    float mx = -1e30f;
    #pragma unroll
    for (int d = 0; d < 32; d++) mx = fmaxf(mx, Ps[t][d]);
    float sum = 0.f;
    float e[32];
    #pragma unroll
    for (int d = 0; d < 32; d++){ e[d] = __expf(Ps[t][d]-mx); sum += e[d]; }
    const float inv = 1.f/sum;
    #pragma unroll
    for (int d = 0; d < 32; d++) Ps[t][d] = e[d]*inv;
  }
  __syncthreads();
  const int n = nb + (t & 63);
  const int cg = t >> 6;
  const size_t vbase = ((size_t)b*768 + 512 + h*32)*NPIX + n;
  float acc[8] = {};
  for (int d = 0; d < 32; d++){
    const float v = qkv[vbase + (size_t)d*NPIX];
    #pragma unroll
    for (int j = 0; j < 8; j++) acc[j] = fmaf(Ps[cg*8+j][d], v, acc[j]);
  }
  const size_t obase = ((size_t)b*256 + h*32 + cg*8)*NPIX + n;
  #pragma unroll
  for (int j = 0; j < 8; j++) out[obase + (size_t)j*NPIX] = acc[j];
}

// ---------------- FFN grouped 3x3 + bias + relu6 ----------------
__global__ void gconv3_kernel(const float* __restrict__ in, const float* __restrict__ w,
                              const float* __restrict__ bias, float* __restrict__ out){
  const int gIdx = blockIdx.x*256 + threadIdx.x;
  const int x = gIdx & 31, y = (gIdx >> 5) & 31;
  const int plane = gIdx >> 10;
  const int o = plane & 511, b = plane >> 9;
  const float* ip = in + ((size_t)b*512 + (o & ~1))*NPIX;
  float s = bias[o];
  #pragma unroll
  for (int ci = 0; ci < 2; ci++){
    #pragma unroll
    for (int ky = 0; ky < 3; ky++){
      const int yy = y + ky - 1;
      if (yy < 0 || yy > 31) continue;
      #pragma unroll
      for (int kx = 0; kx < 3; kx++){
        const int xx = x + kx - 1;
        if (xx < 0 || xx > 31) continue;
        s = fmaf(ip[(size_t)ci*NPIX + yy*32+xx], w[o*18 + ci*9 + ky*3 + kx], s);
      }
    }
  }
  out[gIdx] = fminf(fmaxf(s, 0.f), 6.f);
}

extern "C" void kernel_launch(void* const* d_in, const int* in_sizes, int n_in,
                              void* d_out, int out_size, void* d_ws, size_t ws_size,
                              hipStream_t stream)
{
  (void)in_sizes; (void)n_in; (void)out_size; (void)ws_size;

  float* ws   = (float*)d_ws;
  float* P    = ws;
  float* xbuf = P;
  ushort* Wbf = (ushort*)(ws + OFF_WBF);
  ushort* QT  = (ushort*)(ws + OFF_QT);
  ushort* V16 = (ushort*)(ws + OFF_V16);
  ushort* att = (ushort*)(ws + OFF_ATT);
  float* chaout = ws + OFF_ATT;
  float* buf1 = ws + OFF_BUF1;
  float* buf2 = ws + OFF_BUF2;
  float* spart= ws + OFF_SPART;
  float* stats= ws + OFF_STATS;
  float* eff  = ws + OFF_EFF;
  int*  flag  = (int*)(ws + OFF_FLAG);

  const float* b1f = P + 1976648;
  const float* b3f = P + 2120008;
  const float* w2f = P + 1979208;
  const float* b2f_ = P + 1988424;
  const float* temp = P + 1574976;

  detect_kernel<<<1, 256, 0, stream>>>(d_in[0], flag);
  PackArgs pa;
  for (int i = 0; i < 34; i++) pa.p[i] = d_in[i];
  prep_all_kernel<<<9308, 256, 0, stream>>>(pa, flag, P, Wbf, eff);

  // ---- CDA ----
  ln_stats_kernel<<<64, 256, 0, stream>>>(xbuf, stats, stats+4096);
  gemm_kernel<0,0,false,false><<<dim3(16,24,4), 256, 0, stream>>>(
      xbuf, nullptr, Wbf, nullptr, stats, stats+4096, eff, eff+256,
      nullptr, nullptr, nullptr, nullptr, QT, V16, 256, nullptr);
  attn_kernel<<<dim3(16,8,4), 256, 0, stream>>>(QT, V16, P, eff+2560, att);
  gemm_kernel<2,1,false,false><<<dim3(16,4,4), 256, 0, stream>>>(
      nullptr, att, Wbf+589824, nullptr, nullptr, nullptr, nullptr, nullptr,
      nullptr, nullptr, xbuf, xbuf, nullptr, nullptr, 512, nullptr);

  // ---- CHA ----
  ln_stats_kernel<<<64, 256, 0, stream>>>(xbuf, stats+8192, stats+12288);
  gemm_kernel<0,2,false,false><<<dim3(16,12,4), 256, 0, stream>>>(
      xbuf, nullptr, Wbf+393216, nullptr, stats+8192, stats+12288, eff+512, eff+768,
      nullptr, nullptr, nullptr, buf1, nullptr, nullptr, 256, nullptr);
  dwl2_kernel<<<3072, 256, 0, stream>>>(buf1, P + 1771592, buf2);
  cha_scores_kernel<<<dim3(8,32), 256, 0, stream>>>(buf2, spart);
  cha_pv_kernel<<<dim3(16,32), 256, 0, stream>>>(spart, temp, buf2, chaout);
  gemm_kernel<1,1,false,false><<<dim3(16,4,4), 256, 0, stream>>>(
      chaout, nullptr, Wbf+720896, nullptr, nullptr, nullptr, nullptr, nullptr,
      nullptr, nullptr, xbuf, xbuf, nullptr, nullptr, 256, nullptr);

  // ---- FFN ----
  ln_stats_kernel<<<64, 256, 0, stream>>>(xbuf, stats+16384, stats+20480);
  gemm_kernel<0,2,true,true><<<dim3(16,8,4), 256, 0, stream>>>(
      xbuf, nullptr, Wbf+786432, b1f, stats+16384, stats+20480, eff+1024, eff+1280,
      eff+1536, eff+2048, nullptr, buf1, nullptr, nullptr, 256, nullptr);
  gconv3_kernel<<<8192, 256, 0, stream>>>(buf1, w2f, b2f_, buf2);
  gemm_kernel<1,3,true,false><<<dim3(16,4,4), 256, 0, stream>>>(
      buf2, nullptr, Wbf+917504, b3f, nullptr, nullptr, nullptr, nullptr,
      nullptr, nullptr, xbuf, d_out, nullptr, nullptr, 512, flag);
}

// Round 6
// 303.925 us; speedup vs baseline: 3.2564x; 1.1799x over previous
//
#include <hip/hip_runtime.h>
#include <hip/hip_bf16.h>

typedef __hip_bfloat16 bf16;
typedef __attribute__((ext_vector_type(8))) short s16x8;
typedef __attribute__((ext_vector_type(4))) float f32x4;

#define DEV __device__ __forceinline__

DEV float b2f(bf16 v){ return __bfloat162float(v); }
DEV ushort f2bf(float f){ bf16 h = __float2bfloat16(f); return *reinterpret_cast<ushort*>(&h); }

constexpr int NPIX = 1024;
constexpr float EPSF = 1e-5f;
constexpr float LAMBDA_INIT_F = 0.3555090675909693f;   // 0.8 - 0.6*exp(-0.3)
constexpr float ONE_M_LI     = 0.6444909324090307f;
constexpr float ATT_SCALE    = 0.17677669529663687f;   // 32^-0.5

// workspace offsets (in floats)
constexpr size_t OFF_WBF   = 2120448;   // bf16 weights, 1048576 elems
constexpr size_t OFF_QT    = 2644736;   // QT/KT bf16 [2][4][8][1024][64]
constexpr size_t OFF_V16   = 4741888;   // V bf16 [4][512][1024]
constexpr size_t OFF_ATT   = 5790464;   // att bf16 [4][1024][512]; later chaout f32
constexpr size_t OFF_BUF1  = 6839040;   // f32 [4][768][1024] qkv / ffn1
constexpr size_t OFF_BUF2  = 9984768;   // f32 dw / gconv out
constexpr size_t OFF_SPART = 13130496;
constexpr size_t OFF_STATS = 13425408;  // mu1,r1,mu2,r2,mu3,r3 (6*4096)
constexpr size_t OFF_EFF   = 13449984;  // folded params (2560) + lam(8)
constexpr size_t OFF_FLAG  = 13452608;

struct PackArgs { const void* p[34]; };

// ---------------- dtype detect ----------------
__global__ __launch_bounds__(256) void detect_kernel(const void* __restrict__ x, int* __restrict__ flag){
  __shared__ int sh;
  if (threadIdx.x == 0) sh = 0;
  __syncthreads();
  const bf16* h = (const bf16*)x;
  int local = 0;
  for (int i = threadIdx.x; i < 4096; i += 256){
    float v = b2f(h[i]);
    if (!(fabsf(v) <= 1e6f)) local = 1;
  }
  if (local) atomicOr(&sh, 1);
  __syncthreads();
  if (threadIdx.x == 0) *flag = sh;
}

DEV float rdin(const PackArgs& a, int i, int idx, int flag){
  return flag ? ((const float*)a.p[i])[idx] : b2f(((const bf16*)a.p[i])[idx]);
}

// ---------------- prep_all: pack(8283) + wpack(1024) + prep(1) ----------------
__global__ __launch_bounds__(256) void prep_all_kernel(PackArgs args, const int* __restrict__ flagp,
    float* __restrict__ P, ushort* __restrict__ W, float* __restrict__ eff){
  const int t = threadIdx.x;
  const int blk = blockIdx.x;
  const int flag = *flagp;
  if (blk < 8283){
    constexpr int NIN = 34;
    constexpr int off[NIN+1] = {0,1048576,1048832,1049088,1180160,1311232,1442304,1442560,
      1442816,1443072,1443328,1443392,1574464,1574720,1574976,1574984,1771592,1778504,
      1844040,1844296,1844552,1844808,1845064,1845320,1845576,1976648,1977160,1977672,
      1978184,1978696,1979208,1988424,1988936,2120008,2120264};
    const int g = blk*256 + t;
    if (g >= off[NIN]) return;
    int idx = 0;
    #pragma unroll
    for (int k = 1; k < NIN; k++) idx = (g >= off[k]) ? k : idx;
    P[g] = rdin(args, idx, g - off[idx], flag);
  } else if (blk < 9307){
    // weight bf16 pack straight from inputs
    const int g = (blk - 8283)*1024 + t*4;     // < 1048576, 4 elems, never straddles
    int src, loc;
    if      (g <  131072){ src = 3;  loc = g; }
    else if (g <  262144){ src = 4;  loc = g - 131072; }
    else if (g <  393216){ src = 5;  loc = g - 262144; }
    else if (g <  589824){ src = 15; loc = g - 393216; }
    else if (g <  720896){ src = 11; loc = g - 589824; }
    else if (g <  786432){ src = 17; loc = g - 720896; }
    else if (g <  917504){ src = 24; loc = g - 786432; }
    else                 { src = 32; loc = g - 917504; }
    ushort4 o;
    if (flag){
      const float4 v = *(const float4*)((const float*)args.p[src] + loc);
      o = make_ushort4(f2bf(v.x), f2bf(v.y), f2bf(v.z), f2bf(v.w));
    } else {
      o = *(const ushort4*)((const ushort*)args.p[src] + loc);
    }
    *(ushort4*)&W[g] = o;
  } else {
    // folded params + lambda
    eff[t]      = rdin(args,1,t,flag);  eff[256+t] = rdin(args,2,t,flag);
    eff[512+t]  = rdin(args,12,t,flag); eff[768+t] = rdin(args,13,t,flag);
    const float s1 = rdin(args,20,t,flag) * rsqrtf(rdin(args,23,t,flag) + EPSF);
    eff[1024+t] = rdin(args,18,t,flag) * s1;
    eff[1280+t] = (rdin(args,19,t,flag) - rdin(args,22,t,flag)) * s1 + rdin(args,21,t,flag);
    for (int c = t; c < 512; c += 256){
      const float sc = rdin(args,26,c,flag) * rsqrtf(rdin(args,29,c,flag) + EPSF);
      eff[1536+c] = sc;
      eff[2048+c] = rdin(args,27,c,flag) - rdin(args,28,c,flag)*sc;
    }
    if (t < 8){
      float e1 = 0.f, e2 = 0.f;
      for (int i = 0; i < 32; i++){
        e1 += rdin(args,6,t*32+i,flag) * rdin(args,7,t*32+i,flag);
        e2 += rdin(args,8,t*32+i,flag) * rdin(args,9,t*32+i,flag);
      }
      eff[2560+t] = __expf(e1) - __expf(e2) + LAMBDA_INIT_F;
    }
  }
}

// ---------------- LN stats: mu, rstd per (b, n) ----------------
__global__ __launch_bounds__(256) void ln_stats_kernel(const float* __restrict__ x,
    float* __restrict__ mu, float* __restrict__ rstd){
  __shared__ float ps[16][64], ps2[16][64];
  const int t = threadIdx.x;
  const int b = blockIdx.x >> 4, n0 = (blockIdx.x & 15)*64;
  const int tn = t & 15, tc = t >> 4;
  float4 s = {0,0,0,0}, q = {0,0,0,0};
  #pragma unroll
  for (int i = 0; i < 16; i++){
    const int c = tc*16 + i;
    const float4 v = *(const float4*)&x[((size_t)b*256 + c)*NPIX + n0 + tn*4];
    s.x += v.x; s.y += v.y; s.z += v.z; s.w += v.w;
    q.x += v.x*v.x; q.y += v.y*v.y; q.z += v.z*v.z; q.w += v.w*v.w;
  }
  ps[tc][tn*4+0]=s.x; ps[tc][tn*4+1]=s.y; ps[tc][tn*4+2]=s.z; ps[tc][tn*4+3]=s.w;
  ps2[tc][tn*4+0]=q.x; ps2[tc][tn*4+1]=q.y; ps2[tc][tn*4+2]=q.z; ps2[tc][tn*4+3]=q.w;
  __syncthreads();
  if (t < 64){
    float a = 0.f, qq = 0.f;
    #pragma unroll
    for (int j = 0; j < 16; j++){ a += ps[j][t]; qq += ps2[j][t]; }
    const float m = a * (1.f/256.f);
    float var = qq * (1.f/256.f) - m*m; var = fmaxf(var, 0.f);
    mu[(size_t)b*NPIX + n0 + t] = m;
    rstd[(size_t)b*NPIX + n0 + t] = rsqrtf(var + EPSF);
  }
}

// ---------------- unified MFMA GEMM ----------------
template<int INM, int EPIM, bool BIAS, bool BN2F>
__global__ __launch_bounds__(256) void gemm_kernel(
    const float* __restrict__ Xf, const ushort* __restrict__ Xb, const ushort* __restrict__ W,
    const float* __restrict__ bias, const float* __restrict__ mu, const float* __restrict__ rstd,
    const float* __restrict__ effw, const float* __restrict__ effb,
    const float* __restrict__ s2, const float* __restrict__ t2,
    const float* __restrict__ res, void* __restrict__ out,
    ushort* __restrict__ qt, ushort* __restrict__ v16,
    int Cin, const int* __restrict__ flag)
{
  __shared__ ushort Xt[64][72];
  const int t = threadIdx.x;
  const int nb = blockIdx.x*64, ob = blockIdx.y*64, b = blockIdx.z;
  const int lane = t & 63, w = t >> 6;
  const int wR = w >> 1, wC = w & 1;
  const int l15 = lane & 15, g = lane >> 4;
  const int tn = t & 63, tc4 = t >> 6;
  const f32x4 z4 = {0.f,0.f,0.f,0.f};
  f32x4 acc[2][2] = {{z4,z4},{z4,z4}};

  for (int kb = 0; kb < Cin; kb += 64){
    if (INM == 2){
      const ushort* src = Xb + ((size_t)b*NPIX + nb + tn)*Cin + kb + tc4*16;
      *(uint4*)&Xt[tn][tc4*16]   = *(const uint4*)src;
      *(uint4*)&Xt[tn][tc4*16+8] = *(const uint4*)(src+8);
    } else {
      float m_ = 0.f, r_ = 1.f;
      if (INM == 0){ m_ = mu[(size_t)b*NPIX + nb + tn]; r_ = rstd[(size_t)b*NPIX + nb + tn]; }
      ushort tmp[16];
      #pragma unroll
      for (int i = 0; i < 16; i++){
        const int c = kb + tc4*16 + i;
        float v = Xf[((size_t)b*Cin + c)*NPIX + nb + tn];
        if (INM == 0) v = (v - m_)*r_*effw[c] + effb[c];
        tmp[i] = f2bf(v);
      }
      *(uint4*)&Xt[tn][tc4*16]   = *(uint4*)&tmp[0];
      *(uint4*)&Xt[tn][tc4*16+8] = *(uint4*)&tmp[8];
    }
    __syncthreads();
    #pragma unroll
    for (int ks = 0; ks < 2; ks++){
      const s16x8 a0 = *(const s16x8*)&W[(size_t)(ob + wR*32 + l15)*Cin + kb + ks*32 + g*8];
      const s16x8 a1 = *(const s16x8*)&W[(size_t)(ob + wR*32 + 16 + l15)*Cin + kb + ks*32 + g*8];
      const s16x8 b0 = *(const s16x8*)&Xt[wC*32 + l15][ks*32 + g*8];
      const s16x8 b1 = *(const s16x8*)&Xt[wC*32 + 16 + l15][ks*32 + g*8];
      acc[0][0] = __builtin_amdgcn_mfma_f32_16x16x32_bf16(a0, b0, acc[0][0], 0,0,0);
      acc[0][1] = __builtin_amdgcn_mfma_f32_16x16x32_bf16(a0, b1, acc[0][1], 0,0,0);
      acc[1][0] = __builtin_amdgcn_mfma_f32_16x16x32_bf16(a1, b0, acc[1][0], 0,0,0);
      acc[1][1] = __builtin_amdgcn_mfma_f32_16x16x32_bf16(a1, b1, acc[1][1], 0,0,0);
    }
    __syncthreads();
  }

  const int Cout = gridDim.y*64;
  #pragma unroll
  for (int fr = 0; fr < 2; fr++){
    #pragma unroll
    for (int fc = 0; fc < 2; fc++){
      const int o = ob + wR*32 + fr*16 + 4*g;
      const int n = nb + wC*32 + fc*16 + l15;
      const f32x4 v = acc[fr][fc];
      if (EPIM == 0){
        if (ob < 1024){
          const int qk = o >> 9, h = (o >> 6) & 7, d = o & 63;
          ushort4 pk = make_ushort4(f2bf(v[0]), f2bf(v[1]), f2bf(v[2]), f2bf(v[3]));
          ushort* dst = qt + ((((size_t)qk*4 + b)*8 + h)*NPIX + n)*64 + d;
          *(ushort4*)dst = pk;
        } else {
          const int c = o - 1024;
          #pragma unroll
          for (int r = 0; r < 4; r++)
            v16[((size_t)b*512 + c + r)*NPIX + n] = f2bf(v[r]);
        }
      } else {
        #pragma unroll
        for (int r = 0; r < 4; r++){
          float val = v[r];
          if (BIAS) val += bias[o + r];
          if (BN2F) val = val*s2[o+r] + t2[o+r];
          const size_t row = ((size_t)b*Cout + o + r)*NPIX + n;
          if (EPIM == 1){ ((float*)out)[row] = val + res[row]; }
          else if (EPIM == 2){ ((float*)out)[row] = val; }
          else {
            val += res[row];
            if (*flag) ((float*)out)[row] = val;
            else       ((ushort*)out)[row] = f2bf(val);
          }
        }
      }
    }
  }
}

// ---------------- MFMA differential attention, LDS-staged K/V ----------------
// grid (16 q-tiles, 8 h, 4 b), 256 thr (4 waves x 16 q).
// K,V tiles (64 m x 128B) staged coalesced to LDS, XOR-swizzled (col16 ^= row&7),
// double-buffered; all 4 waves share one copy. S^T = K*Q swapped-QK trick.
__global__ __launch_bounds__(256) void attn_kernel(
    const ushort* __restrict__ QT, const ushort* __restrict__ V16,
    const float* __restrict__ Pf, const float* __restrict__ lamArr,
    ushort* __restrict__ att)
{
  __shared__ ushort Ks[2][4096];   // [buf][row*64 + swz_col_el], 8KB each
  __shared__ ushort Vs[2][4096];
  const int t = threadIdx.x;
  const int lane = t & 63, w = t >> 6;
  const int l15 = lane & 15, g = lane >> 4;
  const int qt = blockIdx.x, h = blockIdx.y, b = blockIdx.z;
  const int qsub = qt*64 + w*16;
  const ushort* Qb = QT + ((size_t)b*8 + h)*NPIX*64;
  const ushort* Kb = QT + ((size_t)(4 + b)*8 + h)*NPIX*64;
  const ushort* Vb = V16 + ((size_t)b*512 + h*64)*NPIX;

  // staging chunk assignment: chunks c = t, t+256 (512 x 16B per tile)
  const int c0row = t >> 3, c0col = t & 7;           // chunk t
  const int c1row = (t + 256) >> 3, c1col = t & 7;   // chunk t+256
  const int sw0 = (c0col ^ (c0row & 7))*8;
  const int sw1 = (c1col ^ (c1row & 7))*8;

  s16x8 bq[2];
  #pragma unroll
  for (int hx = 0; hx < 2; hx++)
    bq[hx] = *(const s16x8*)&Qb[(size_t)(qsub + l15)*64 + 32*hx + 8*g];
  const float lam = lamArr[h];

  const f32x4 z4 = {0.f,0.f,0.f,0.f};
  f32x4 o0[4] = {z4,z4,z4,z4};
  f32x4 o1[4] = {z4,z4,z4,z4};
  float z[2] = {0.f, 0.f};

  // prologue: tile 0 -> buf0; issue tile 1 loads
  uint4 kra = *(const uint4*)&Kb[(size_t)c0row*64 + c0col*8];
  uint4 krb = *(const uint4*)&Kb[(size_t)c1row*64 + c1col*8];
  uint4 vra = *(const uint4*)&Vb[(size_t)c0row*NPIX + c0col*8];
  uint4 vrb = *(const uint4*)&Vb[(size_t)c1row*NPIX + c1col*8];
  *(uint4*)&Ks[0][c0row*64 + sw0] = kra;
  *(uint4*)&Ks[0][c1row*64 + sw1] = krb;
  *(uint4*)&Vs[0][c0row*64 + sw0] = vra;
  *(uint4*)&Vs[0][c1row*64 + sw1] = vrb;
  kra = *(const uint4*)&Kb[(size_t)(64 + c0row)*64 + c0col*8];
  krb = *(const uint4*)&Kb[(size_t)(64 + c1row)*64 + c1col*8];
  vra = *(const uint4*)&Vb[(size_t)c0row*NPIX + 64 + c0col*8];
  vrb = *(const uint4*)&Vb[(size_t)c1row*NPIX + 64 + c1col*8];
  __syncthreads();

  #pragma unroll 1
  for (int it = 0; it < 16; it++){
    const int cur = it & 1;
    const ushort* Kc = &Ks[cur][0];
    const ushort* Vc = &Vs[cur][0];

    // QK^T (swapped): s[hx][fr][r] = S[m = fr*16 + 4g + r][q = l15]
    f32x4 s[2][4];
    #pragma unroll
    for (int fr = 0; fr < 4; fr++){
      const int row = fr*16 + l15;
      const int rx = (row & 7)*8;
      #pragma unroll
      for (int hx = 0; hx < 2; hx++){
        const s16x8 ak = *(const s16x8*)&Kc[row*64 + ((hx*32 + 8*g) ^ rx)];
        s[hx][fr] = __builtin_amdgcn_mfma_f32_16x16x32_bf16(ak, bq[hx], z4, 0,0,0);
      }
    }
    // exp + Z + pack into PV A-fragments: pa[hx][ms] slot j=(fr&1)*4+r
    s16x8 pa[2][2];
    #pragma unroll
    for (int hx = 0; hx < 2; hx++){
      #pragma unroll
      for (int ms = 0; ms < 2; ms++){
        ushort tmp[8];
        #pragma unroll
        for (int fr2 = 0; fr2 < 2; fr2++)
          #pragma unroll
          for (int r = 0; r < 4; r++){
            const float e = __expf(s[hx][ms*2 + fr2][r] * ATT_SCALE);
            z[hx] += e;
            tmp[fr2*4 + r] = f2bf(e);
          }
        pa[hx][ms] = *(s16x8*)tmp;
      }
    }
    // PV
    __builtin_amdgcn_s_setprio(1);
    #pragma unroll
    for (int ms = 0; ms < 2; ms++){
      #pragma unroll
      for (int dc = 0; dc < 4; dc++){
        const int row = dc*16 + l15;
        const int r7 = row & 7;
        const int elo = ms*32 + 4*g;
        const int eloswz = ((((elo >> 3) ^ r7) << 3) | (elo & 7));
        const int ehi = elo + 16;
        const int ehiswz = ((((ehi >> 3) ^ r7) << 3) | (ehi & 7));
        const uint2 lo = *(const uint2*)&Vc[row*64 + eloswz];
        const uint2 hi = *(const uint2*)&Vc[row*64 + ehiswz];
        union { uint u[4]; s16x8 v; } bv;
        bv.u[0] = lo.x; bv.u[1] = lo.y; bv.u[2] = hi.x; bv.u[3] = hi.y;
        o0[dc] = __builtin_amdgcn_mfma_f32_16x16x32_bf16(pa[0][ms], bv.v, o0[dc], 0,0,0);
        o1[dc] = __builtin_amdgcn_mfma_f32_16x16x32_bf16(pa[1][ms], bv.v, o1[dc], 0,0,0);
      }
    }
    __builtin_amdgcn_s_setprio(0);

    if (it < 15){
      const int nxt = cur ^ 1;
      *(uint4*)&Ks[nxt][c0row*64 + sw0] = kra;
      *(uint4*)&Ks[nxt][c1row*64 + sw1] = krb;
      *(uint4*)&Vs[nxt][c0row*64 + sw0] = vra;
      *(uint4*)&Vs[nxt][c1row*64 + sw1] = vrb;
      if (it < 14){
        const int m0 = (it + 2)*64;
        kra = *(const uint4*)&Kb[(size_t)(m0 + c0row)*64 + c0col*8];
        krb = *(const uint4*)&Kb[(size_t)(m0 + c1row)*64 + c1col*8];
        vra = *(const uint4*)&Vb[(size_t)c0row*NPIX + m0 + c0col*8];
        vrb = *(const uint4*)&Vb[(size_t)c1row*NPIX + m0 + c1col*8];
      }
    }
    __syncthreads();
  }

  // Z: reduce over g-groups; every lane gets Z[q=l15]
  #pragma unroll
  for (int hx = 0; hx < 2; hx++){
    z[hx] += __shfl_xor(z[hx], 16);
    z[hx] += __shfl_xor(z[hx], 32);
  }
  float zi0[4], zi1[4];
  #pragma unroll
  for (int r = 0; r < 4; r++){
    zi0[r] = 1.f / __shfl(z[0], 4*g + r);
    zi1[r] = 1.f / __shfl(z[1], 4*g + r);
  }
  float val[4][4];
  float ss[4] = {0.f,0.f,0.f,0.f};
  #pragma unroll
  for (int dc = 0; dc < 4; dc++)
    #pragma unroll
    for (int r = 0; r < 4; r++){
      const float vv = o0[dc][r]*zi0[r] - lam*o1[dc][r]*zi1[r];
      val[dc][r] = vv; ss[r] += vv*vv;
    }
  #pragma unroll
  for (int r = 0; r < 4; r++){
    ss[r] += __shfl_xor(ss[r], 1);
    ss[r] += __shfl_xor(ss[r], 2);
    ss[r] += __shfl_xor(ss[r], 4);
    ss[r] += __shfl_xor(ss[r], 8);
  }
  float rinv[4];
  #pragma unroll
  for (int r = 0; r < 4; r++) rinv[r] = ONE_M_LI * rsqrtf(ss[r]*(1.f/64.f) + EPSF);
  #pragma unroll
  for (int dc = 0; dc < 4; dc++){
    const float rs = Pf[1443328 + dc*16 + l15];
    #pragma unroll
    for (int r = 0; r < 4; r++){
      const int n = qsub + 4*g + r;
      att[((size_t)b*NPIX + n)*512 + h*64 + dc*16 + l15] = f2bf(val[dc][r]*rinv[r]*rs);
    }
  }
}

// ---------------- fused depthwise 3x3 + L2-norm (block = plane) ----------------
__global__ __launch_bounds__(256) void dwl2_kernel(const float* __restrict__ in,
    const float* __restrict__ wdw, float* __restrict__ out){
  __shared__ float tile[1024];
  __shared__ float wsum[4];
  const int p = blockIdx.x;                 // b*768 + c
  const int c = p % 768;
  const int t = threadIdx.x;
  const float* ip = in + (size_t)p*1024;
  *(float4*)&tile[t*4] = *(const float4*)&ip[t*4];
  float wv[9];
  #pragma unroll
  for (int i = 0; i < 9; i++) wv[i] = wdw[c*9+i];
  __syncthreads();
  float o[4]; float ssq = 0.f;
  #pragma unroll
  for (int j = 0; j < 4; j++){
    const int px = t*4 + j, x = px & 31, y = px >> 5;
    float s = 0.f;
    #pragma unroll
    for (int ky = 0; ky < 3; ky++){
      const int yy = y + ky - 1;
      if (yy < 0 || yy > 31) continue;
      #pragma unroll
      for (int kx = 0; kx < 3; kx++){
        const int xx = x + kx - 1;
        if (xx < 0 || xx > 31) continue;
        s = fmaf(tile[yy*32+xx], wv[ky*3+kx], s);
      }
    }
    o[j] = s; ssq += s*s;
  }
  for (int off = 32; off; off >>= 1) ssq += __shfl_down(ssq, off);
  if ((t & 63) == 0) wsum[t >> 6] = ssq;
  __syncthreads();
  float inv = 1.f;
  if (c < 512){
    const float tot = wsum[0]+wsum[1]+wsum[2]+wsum[3];
    inv = 1.f / fmaxf(sqrtf(tot), 1e-12f);
  }
  *(float4*)&out[(size_t)p*1024 + t*4] = make_float4(o[0]*inv, o[1]*inv, o[2]*inv, o[3]*inv);
}

// ---------------- CHA partial scores ----------------
__global__ __launch_bounds__(256) void cha_scores_kernel(const float* __restrict__ qk,
                                                         float* __restrict__ spart){
  __shared__ float qs[32][129];
  __shared__ float ks[32][129];
  const int t = threadIdx.x;
  const int nb = blockIdx.x*128;
  const int bh = blockIdx.y, b = bh >> 3, h = bh & 7;
  const size_t qbase = ((size_t)b*768 + h*32)*NPIX + nb;
  const size_t kbase = qbase + (size_t)256*NPIX;
  { const int c = t >> 3, n0 = (t & 7)*16;
    #pragma unroll
    for (int j = 0; j < 16; j++){
      qs[c][n0+j] = qk[qbase + (size_t)c*NPIX + n0 + j];
      ks[c][n0+j] = qk[kbase + (size_t)c*NPIX + n0 + j];
    } }
  __syncthreads();
  const int c = t & 31, dg = t >> 5;
  float acc[4] = {};
  for (int nn = 0; nn < 128; nn++){
    const float qv = qs[c][nn];
    #pragma unroll
    for (int j = 0; j < 4; j++) acc[j] = fmaf(qv, ks[dg*4+j][nn], acc[j]);
  }
  float* sp = spart + ((size_t)bh*8 + blockIdx.x)*1024 + c*32 + dg*4;
  #pragma unroll
  for (int j = 0; j < 4; j++) sp[j] = acc[j];
}

// ---------------- CHA softmax + PV (fused) ----------------
__global__ __launch_bounds__(256) void cha_pv_kernel(const float* __restrict__ spart,
    const float* __restrict__ tempP, const float* __restrict__ qkv, float* __restrict__ out){
  __shared__ float Ps[32][33];
  const int t = threadIdx.x;
  const int bh = blockIdx.y, b = bh >> 3, h = bh & 7;
  const int nb = blockIdx.x*64;
  const float tf = tempP[h];
  for (int p = t; p < 1024; p += 256){
    float s = 0.f;
    #pragma unroll
    for (int ch = 0; ch < 8; ch++) s += spart[((size_t)bh*8 + ch)*1024 + p];
    Ps[p >> 5][p & 31] = s * tf;
  }
  __syncthreads();
  if (t < 32){
    float mx = -1e30f;
    #pragma unroll
    for (int d = 0; d < 32; d++) mx = fmaxf(mx, Ps[t][d]);
    float sum = 0.f;
    float e[32];
    #pragma unroll
    for (int d = 0; d < 32; d++){ e[d] = __expf(Ps[t][d]-mx); sum += e[d]; }
    const float inv = 1.f/sum;
    #pragma unroll
    for (int d = 0; d < 32; d++) Ps[t][d] = e[d]*inv;
  }
  __syncthreads();
  const int n = nb + (t & 63);
  const int cg = t >> 6;
  const size_t vbase = ((size_t)b*768 + 512 + h*32)*NPIX + n;
  float acc[8] = {};
  for (int d = 0; d < 32; d++){
    const float v = qkv[vbase + (size_t)d*NPIX];
    #pragma unroll
    for (int j = 0; j < 8; j++) acc[j] = fmaf(Ps[cg*8+j][d], v, acc[j]);
  }
  const size_t obase = ((size_t)b*256 + h*32 + cg*8)*NPIX + n;
  #pragma unroll
  for (int j = 0; j < 8; j++) out[obase + (size_t)j*NPIX] = acc[j];
}

// ---------------- FFN grouped 3x3 + bias + relu6 ----------------
__global__ void gconv3_kernel(const float* __restrict__ in, const float* __restrict__ w,
                              const float* __restrict__ bias, float* __restrict__ out){
  const int gIdx = blockIdx.x*256 + threadIdx.x;
  const int x = gIdx & 31, y = (gIdx >> 5) & 31;
  const int plane = gIdx >> 10;
  const int o = plane & 511, b = plane >> 9;
  const float* ip = in + ((size_t)b*512 + (o & ~1))*NPIX;
  float s = bias[o];
  #pragma unroll
  for (int ci = 0; ci < 2; ci++){
    #pragma unroll
    for (int ky = 0; ky < 3; ky++){
      const int yy = y + ky - 1;
      if (yy < 0 || yy > 31) continue;
      #pragma unroll
      for (int kx = 0; kx < 3; kx++){
        const int xx = x + kx - 1;
        if (xx < 0 || xx > 31) continue;
        s = fmaf(ip[(size_t)ci*NPIX + yy*32+xx], w[o*18 + ci*9 + ky*3 + kx], s);
      }
    }
  }
  out[gIdx] = fminf(fmaxf(s, 0.f), 6.f);
}

extern "C" void kernel_launch(void* const* d_in, const int* in_sizes, int n_in,
                              void* d_out, int out_size, void* d_ws, size_t ws_size,
                              hipStream_t stream)
{
  (void)in_sizes; (void)n_in; (void)out_size; (void)ws_size;

  float* ws   = (float*)d_ws;
  float* P    = ws;
  float* xbuf = P;
  ushort* Wbf = (ushort*)(ws + OFF_WBF);
  ushort* QT  = (ushort*)(ws + OFF_QT);
  ushort* V16 = (ushort*)(ws + OFF_V16);
  ushort* att = (ushort*)(ws + OFF_ATT);
  float* chaout = ws + OFF_ATT;
  float* buf1 = ws + OFF_BUF1;
  float* buf2 = ws + OFF_BUF2;
  float* spart= ws + OFF_SPART;
  float* stats= ws + OFF_STATS;
  float* eff  = ws + OFF_EFF;
  int*  flag  = (int*)(ws + OFF_FLAG);

  const float* b1f = P + 1976648;
  const float* b3f = P + 2120008;
  const float* w2f = P + 1979208;
  const float* b2f_ = P + 1988424;
  const float* temp = P + 1574976;

  detect_kernel<<<1, 256, 0, stream>>>(d_in[0], flag);
  PackArgs pa;
  for (int i = 0; i < 34; i++) pa.p[i] = d_in[i];
  prep_all_kernel<<<9308, 256, 0, stream>>>(pa, flag, P, Wbf, eff);

  // ---- CDA ----
  ln_stats_kernel<<<64, 256, 0, stream>>>(xbuf, stats, stats+4096);
  gemm_kernel<0,0,false,false><<<dim3(16,24,4), 256, 0, stream>>>(
      xbuf, nullptr, Wbf, nullptr, stats, stats+4096, eff, eff+256,
      nullptr, nullptr, nullptr, nullptr, QT, V16, 256, nullptr);
  attn_kernel<<<dim3(16,8,4), 256, 0, stream>>>(QT, V16, P, eff+2560, att);
  gemm_kernel<2,1,false,false><<<dim3(16,4,4), 256, 0, stream>>>(
      nullptr, att, Wbf+589824, nullptr, nullptr, nullptr, nullptr, nullptr,
      nullptr, nullptr, xbuf, xbuf, nullptr, nullptr, 512, nullptr);

  // ---- CHA ----
  ln_stats_kernel<<<64, 256, 0, stream>>>(xbuf, stats+8192, stats+12288);
  gemm_kernel<0,2,false,false><<<dim3(16,12,4), 256, 0, stream>>>(
      xbuf, nullptr, Wbf+393216, nullptr, stats+8192, stats+12288, eff+512, eff+768,
      nullptr, nullptr, nullptr, buf1, nullptr, nullptr, 256, nullptr);
  dwl2_kernel<<<3072, 256, 0, stream>>>(buf1, P + 1771592, buf2);
  cha_scores_kernel<<<dim3(8,32), 256, 0, stream>>>(buf2, spart);
  cha_pv_kernel<<<dim3(16,32), 256, 0, stream>>>(spart, temp, buf2, chaout);
  gemm_kernel<1,1,false,false><<<dim3(16,4,4), 256, 0, stream>>>(
      chaout, nullptr, Wbf+720896, nullptr, nullptr, nullptr, nullptr, nullptr,
      nullptr, nullptr, xbuf, xbuf, nullptr, nullptr, 256, nullptr);

  // ---- FFN ----
  ln_stats_kernel<<<64, 256, 0, stream>>>(xbuf, stats+16384, stats+20480);
  gemm_kernel<0,2,true,true><<<dim3(16,8,4), 256, 0, stream>>>(
      xbuf, nullptr, Wbf+786432, b1f, stats+16384, stats+20480, eff+1024, eff+1280,
      eff+1536, eff+2048, nullptr, buf1, nullptr, nullptr, 256, nullptr);
  gconv3_kernel<<<8192, 256, 0, stream>>>(buf1, w2f, b2f_, buf2);
  gemm_kernel<1,3,true,false><<<dim3(16,4,4), 256, 0, stream>>>(
      buf2, nullptr, Wbf+917504, b3f, nullptr, nullptr, nullptr, nullptr,
      nullptr, nullptr, xbuf, d_out, nullptr, nullptr, 512, flag);
}

// Round 7
// 285.889 us; speedup vs baseline: 3.4619x; 1.0631x over previous
//
#include <hip/hip_runtime.h>
#include <hip/hip_bf16.h>

typedef __hip_bfloat16 bf16;
typedef __attribute__((ext_vector_type(8))) short s16x8;
typedef __attribute__((ext_vector_type(4))) float f32x4;

#define DEV __device__ __forceinline__

DEV float b2f(bf16 v){ return __bfloat162float(v); }
DEV ushort f2bf(float f){ bf16 h = __float2bfloat16(f); return *reinterpret_cast<ushort*>(&h); }

constexpr int NPIX = 1024;
constexpr float EPSF = 1e-5f;
constexpr float LAMBDA_INIT_F = 0.3555090675909693f;   // 0.8 - 0.6*exp(-0.3)
constexpr float ONE_M_LI     = 0.6444909324090307f;
constexpr float ATT_SCALE    = 0.17677669529663687f;   // 32^-0.5

// workspace offsets (in floats)
constexpr size_t OFF_WBF   = 2120448;   // bf16 weights, 1048576 elems
constexpr size_t OFF_QT    = 2644736;   // QT/KT bf16 [2][4][8][1024][64]
constexpr size_t OFF_V16   = 4741888;   // V bf16 [4][512][1024]
constexpr size_t OFF_ATT   = 5790464;   // att bf16 [4][1024][512]; later chaout f32
constexpr size_t OFF_BUF1  = 6839040;   // f32 [4][768][1024] qkv / ffn1
constexpr size_t OFF_BUF2  = 9984768;   // f32 dw / gconv out
constexpr size_t OFF_SPART = 13130496;
constexpr size_t OFF_STATS = 13425408;  // 3 sections x [sum 4096 | sq 4096]
constexpr size_t OFF_EFF   = 13449984;  // folded params (2560) + lam(8)
constexpr size_t OFF_FLAG  = 13452608;

struct PackArgs { const void* p[34]; };

// ---------------- dtype detect ----------------
__global__ __launch_bounds__(256) void detect_kernel(const void* __restrict__ x, int* __restrict__ flag){
  __shared__ int sh;
  if (threadIdx.x == 0) sh = 0;
  __syncthreads();
  const bf16* h = (const bf16*)x;
  int local = 0;
  for (int i = threadIdx.x; i < 4096; i += 256){
    float v = b2f(h[i]);
    if (!(fabsf(v) <= 1e6f)) local = 1;
  }
  if (local) atomicOr(&sh, 1);
  __syncthreads();
  if (threadIdx.x == 0) *flag = sh;
}

DEV float rdin(const PackArgs& a, int i, int idx, int flag){
  return flag ? ((const float*)a.p[i])[idx] : b2f(((const bf16*)a.p[i])[idx]);
}

// ---------------- prep_all: pack + wpack + params + zero-stats + LN1 stats ----------------
__global__ __launch_bounds__(256) void prep_all_kernel(PackArgs args, const int* __restrict__ flagp,
    float* __restrict__ P, ushort* __restrict__ W, float* __restrict__ eff, float* __restrict__ stats){
  __shared__ float ps[16][64], ps2[16][64];
  const int t = threadIdx.x;
  const int blk = blockIdx.x;
  const int flag = *flagp;
  if (blk < 8283){
    constexpr int NIN = 34;
    constexpr int off[NIN+1] = {0,1048576,1048832,1049088,1180160,1311232,1442304,1442560,
      1442816,1443072,1443328,1443392,1574464,1574720,1574976,1574984,1771592,1778504,
      1844040,1844296,1844552,1844808,1845064,1845320,1845576,1976648,1977160,1977672,
      1978184,1978696,1979208,1988424,1988936,2120008,2120264};
    const int g = blk*256 + t;
    if (g >= off[NIN]) return;
    int idx = 0;
    #pragma unroll
    for (int k = 1; k < NIN; k++) idx = (g >= off[k]) ? k : idx;
    P[g] = rdin(args, idx, g - off[idx], flag);
  } else if (blk < 9307){
    // weight bf16 pack straight from inputs
    const int g = (blk - 8283)*1024 + t*4;     // < 1048576, 4 elems, never straddles
    int src, loc;
    if      (g <  131072){ src = 3;  loc = g; }
    else if (g <  262144){ src = 4;  loc = g - 131072; }
    else if (g <  393216){ src = 5;  loc = g - 262144; }
    else if (g <  589824){ src = 15; loc = g - 393216; }
    else if (g <  720896){ src = 11; loc = g - 589824; }
    else if (g <  786432){ src = 17; loc = g - 720896; }
    else if (g <  917504){ src = 24; loc = g - 786432; }
    else                 { src = 32; loc = g - 917504; }
    ushort4 o;
    if (flag){
      const float4 v = *(const float4*)((const float*)args.p[src] + loc);
      o = make_ushort4(f2bf(v.x), f2bf(v.y), f2bf(v.z), f2bf(v.w));
    } else {
      o = *(const ushort4*)((const ushort*)args.p[src] + loc);
    }
    *(ushort4*)&W[g] = o;
  } else if (blk == 9307){
    // folded params + lambda + zero stats2/stats3 accumulators
    eff[t]      = rdin(args,1,t,flag);  eff[256+t] = rdin(args,2,t,flag);
    eff[512+t]  = rdin(args,12,t,flag); eff[768+t] = rdin(args,13,t,flag);
    const float s1 = rdin(args,20,t,flag) * rsqrtf(rdin(args,23,t,flag) + EPSF);
    eff[1024+t] = rdin(args,18,t,flag) * s1;
    eff[1280+t] = (rdin(args,19,t,flag) - rdin(args,22,t,flag)) * s1 + rdin(args,21,t,flag);
    for (int c = t; c < 512; c += 256){
      const float sc = rdin(args,26,c,flag) * rsqrtf(rdin(args,29,c,flag) + EPSF);
      eff[1536+c] = sc;
      eff[2048+c] = rdin(args,27,c,flag) - rdin(args,28,c,flag)*sc;
    }
    if (t < 8){
      float e1 = 0.f, e2 = 0.f;
      for (int i = 0; i < 32; i++){
        e1 += rdin(args,6,t*32+i,flag) * rdin(args,7,t*32+i,flag);
        e2 += rdin(args,8,t*32+i,flag) * rdin(args,9,t*32+i,flag);
      }
      eff[2560+t] = __expf(e1) - __expf(e2) + LAMBDA_INIT_F;
    }
    for (int i = t; i < 16384; i += 256) stats[8192 + i] = 0.f;
  } else {
    // blk 9308..9371: LN1 raw stats from d_in x
    const int bi = blk - 9308;
    const int b = bi >> 4, n0 = (bi & 15)*64;
    const int tn = t & 15, tc = t >> 4;
    float s = 0.f, q = 0.f;
    #pragma unroll 4
    for (int i = 0; i < 16; i++){
      const int c = tc*16 + i;
      #pragma unroll
      for (int j = 0; j < 4; j++){
        const float v = rdin(args, 0, ((b*256 + c) << 10) + n0 + tn*4 + j, flag);
        s += v; q += v*v;
      }
    }
    ps[tc][tn*4+0] = 0.f;  // unused slots avoided: write per-thread partials
    ps[tc][tn*4] = 0.f;
    // store partials: each thread covers 4 n's worth? No: thread covers n0+tn*4..+3 over 16 ch.
    // Use [tc][tn*4+j] accumulation: redo with per-j partials.
    float sj[4] = {0,0,0,0}, qj[4] = {0,0,0,0};
    #pragma unroll 4
    for (int i = 0; i < 16; i++){
      const int c = tc*16 + i;
      #pragma unroll
      for (int j = 0; j < 4; j++){
        const float v = rdin(args, 0, ((b*256 + c) << 10) + n0 + tn*4 + j, flag);
        sj[j] += v; qj[j] += v*v;
      }
    }
    #pragma unroll
    for (int j = 0; j < 4; j++){ ps[tc][tn*4+j] = sj[j]; ps2[tc][tn*4+j] = qj[j]; }
    __syncthreads();
    if (t < 64){
      float a = 0.f, qq = 0.f;
      #pragma unroll
      for (int j2 = 0; j2 < 16; j2++){ a += ps[j2][t]; qq += ps2[j2][t]; }
      stats[(size_t)b*NPIX + n0 + t] = a;
      stats[4096 + (size_t)b*NPIX + n0 + t] = qq;
    }
  }
}

// ---------------- unified MFMA GEMM ----------------
// IN: 0 = f32 [c][n] + LN(raw stats); 1 = f32 plain; 2 = bf16 [b][n][Cin]
// EPI: 0 = QKV special; 1 = f32 +res (opt STATS accum); 2 = f32 (+bias)(+bn2); 3 = final
template<int INM, int EPIM, bool BIAS, bool BN2F, bool STATS>
__global__ __launch_bounds__(256) void gemm_kernel(
    const float* __restrict__ Xf, const ushort* __restrict__ Xb, const ushort* __restrict__ W,
    const float* __restrict__ bias, const float* __restrict__ mu, const float* __restrict__ rstd,
    const float* __restrict__ effw, const float* __restrict__ effb,
    const float* __restrict__ s2, const float* __restrict__ t2,
    const float* __restrict__ res, void* __restrict__ out,
    ushort* __restrict__ qt, ushort* __restrict__ v16,
    float* __restrict__ gstats,
    int Cin, const int* __restrict__ flag)
{
  __shared__ ushort Xt[64][72];
  const int t = threadIdx.x;
  const int nb = blockIdx.x*64, ob = blockIdx.y*64, b = blockIdx.z;
  const int lane = t & 63, w = t >> 6;
  const int wR = w >> 1, wC = w & 1;
  const int l15 = lane & 15, g = lane >> 4;
  const int tn = t & 63, tc4 = t >> 6;
  const f32x4 z4 = {0.f,0.f,0.f,0.f};
  f32x4 acc[2][2] = {{z4,z4},{z4,z4}};

  for (int kb = 0; kb < Cin; kb += 64){
    if (INM == 2){
      const ushort* src = Xb + ((size_t)b*NPIX + nb + tn)*Cin + kb + tc4*16;
      *(uint4*)&Xt[tn][tc4*16]   = *(const uint4*)src;
      *(uint4*)&Xt[tn][tc4*16+8] = *(const uint4*)(src+8);
    } else {
      float m_ = 0.f, r_ = 1.f;
      if (INM == 0){
        const float sv = mu[(size_t)b*NPIX + nb + tn];
        const float qv = rstd[(size_t)b*NPIX + nb + tn];
        m_ = sv * (1.f/256.f);
        const float var = qv*(1.f/256.f) - m_*m_;
        r_ = rsqrtf(fmaxf(var, 0.f) + EPSF);
      }
      ushort tmp[16];
      #pragma unroll
      for (int i = 0; i < 16; i++){
        const int c = kb + tc4*16 + i;
        float v = Xf[((size_t)b*Cin + c)*NPIX + nb + tn];
        if (INM == 0) v = (v - m_)*r_*effw[c] + effb[c];
        tmp[i] = f2bf(v);
      }
      *(uint4*)&Xt[tn][tc4*16]   = *(uint4*)&tmp[0];
      *(uint4*)&Xt[tn][tc4*16+8] = *(uint4*)&tmp[8];
    }
    __syncthreads();
    #pragma unroll
    for (int ks = 0; ks < 2; ks++){
      const s16x8 a0 = *(const s16x8*)&W[(size_t)(ob + wR*32 + l15)*Cin + kb + ks*32 + g*8];
      const s16x8 a1 = *(const s16x8*)&W[(size_t)(ob + wR*32 + 16 + l15)*Cin + kb + ks*32 + g*8];
      const s16x8 b0 = *(const s16x8*)&Xt[wC*32 + l15][ks*32 + g*8];
      const s16x8 b1 = *(const s16x8*)&Xt[wC*32 + 16 + l15][ks*32 + g*8];
      acc[0][0] = __builtin_amdgcn_mfma_f32_16x16x32_bf16(a0, b0, acc[0][0], 0,0,0);
      acc[0][1] = __builtin_amdgcn_mfma_f32_16x16x32_bf16(a0, b1, acc[0][1], 0,0,0);
      acc[1][0] = __builtin_amdgcn_mfma_f32_16x16x32_bf16(a1, b0, acc[1][0], 0,0,0);
      acc[1][1] = __builtin_amdgcn_mfma_f32_16x16x32_bf16(a1, b1, acc[1][1], 0,0,0);
    }
    __syncthreads();
  }

  const int Cout = gridDim.y*64;
  float sst[2] = {0.f, 0.f}, qst[2] = {0.f, 0.f};
  #pragma unroll
  for (int fr = 0; fr < 2; fr++){
    #pragma unroll
    for (int fc = 0; fc < 2; fc++){
      const int o = ob + wR*32 + fr*16 + 4*g;
      const int n = nb + wC*32 + fc*16 + l15;
      const f32x4 v = acc[fr][fc];
      if (EPIM == 0){
        if (ob < 1024){
          const int qk = o >> 9, h = (o >> 6) & 7, d = o & 63;
          ushort4 pk = make_ushort4(f2bf(v[0]), f2bf(v[1]), f2bf(v[2]), f2bf(v[3]));
          ushort* dst = qt + ((((size_t)qk*4 + b)*8 + h)*NPIX + n)*64 + d;
          *(ushort4*)dst = pk;
        } else {
          const int c = o - 1024;
          #pragma unroll
          for (int r = 0; r < 4; r++)
            v16[((size_t)b*512 + c + r)*NPIX + n] = f2bf(v[r]);
        }
      } else {
        #pragma unroll
        for (int r = 0; r < 4; r++){
          float val = v[r];
          if (BIAS) val += bias[o + r];
          if (BN2F) val = val*s2[o+r] + t2[o+r];
          const size_t row = ((size_t)b*Cout + o + r)*NPIX + n;
          if (EPIM == 1){
            const float vf = val + res[row];
            ((float*)out)[row] = vf;
            if (STATS){ sst[fc] += vf; qst[fc] += vf*vf; }
          }
          else if (EPIM == 2){ ((float*)out)[row] = val; }
          else {
            val += res[row];
            if (*flag) ((float*)out)[row] = val;
            else       ((ushort*)out)[row] = f2bf(val);
          }
        }
      }
    }
  }
  if (STATS){
    float* sacc = (float*)&Xt[0][0];
    if (t < 128) sacc[t] = 0.f;
    __syncthreads();
    #pragma unroll
    for (int fc = 0; fc < 2; fc++){
      const int nl = wC*32 + fc*16 + l15;
      atomicAdd(&sacc[nl*2+0], sst[fc]);
      atomicAdd(&sacc[nl*2+1], qst[fc]);
    }
    __syncthreads();
    if (t < 64){
      atomicAdd(&gstats[(size_t)b*NPIX + nb + t],        sacc[t*2+0]);
      atomicAdd(&gstats[4096 + (size_t)b*NPIX + nb + t], sacc[t*2+1]);
    }
  }
}

// ---------------- MFMA differential attention, LDS-staged K/V ----------------
__global__ __launch_bounds__(256) void attn_kernel(
    const ushort* __restrict__ QT, const ushort* __restrict__ V16,
    const float* __restrict__ Pf, const float* __restrict__ lamArr,
    ushort* __restrict__ att)
{
  __shared__ ushort Ks[2][4096];
  __shared__ ushort Vs[2][4096];
  const int t = threadIdx.x;
  const int lane = t & 63, w = t >> 6;
  const int l15 = lane & 15, g = lane >> 4;
  const int qt = blockIdx.x, h = blockIdx.y, b = blockIdx.z;
  const int qsub = qt*64 + w*16;
  const ushort* Qb = QT + ((size_t)b*8 + h)*NPIX*64;
  const ushort* Kb = QT + ((size_t)(4 + b)*8 + h)*NPIX*64;
  const ushort* Vb = V16 + ((size_t)b*512 + h*64)*NPIX;

  const int c0row = t >> 3, c0col = t & 7;
  const int c1row = (t + 256) >> 3, c1col = t & 7;
  const int sw0 = (c0col ^ (c0row & 7))*8;
  const int sw1 = (c1col ^ (c1row & 7))*8;

  s16x8 bq[2];
  #pragma unroll
  for (int hx = 0; hx < 2; hx++)
    bq[hx] = *(const s16x8*)&Qb[(size_t)(qsub + l15)*64 + 32*hx + 8*g];
  const float lam = lamArr[h];

  const f32x4 z4 = {0.f,0.f,0.f,0.f};
  f32x4 o0[4] = {z4,z4,z4,z4};
  f32x4 o1[4] = {z4,z4,z4,z4};
  float z[2] = {0.f, 0.f};

  uint4 kra = *(const uint4*)&Kb[(size_t)c0row*64 + c0col*8];
  uint4 krb = *(const uint4*)&Kb[(size_t)c1row*64 + c1col*8];
  uint4 vra = *(const uint4*)&Vb[(size_t)c0row*NPIX + c0col*8];
  uint4 vrb = *(const uint4*)&Vb[(size_t)c1row*NPIX + c1col*8];
  *(uint4*)&Ks[0][c0row*64 + sw0] = kra;
  *(uint4*)&Ks[0][c1row*64 + sw1] = krb;
  *(uint4*)&Vs[0][c0row*64 + sw0] = vra;
  *(uint4*)&Vs[0][c1row*64 + sw1] = vrb;
  kra = *(const uint4*)&Kb[(size_t)(64 + c0row)*64 + c0col*8];
  krb = *(const uint4*)&Kb[(size_t)(64 + c1row)*64 + c1col*8];
  vra = *(const uint4*)&Vb[(size_t)c0row*NPIX + 64 + c0col*8];
  vrb = *(const uint4*)&Vb[(size_t)c1row*NPIX + 64 + c1col*8];
  __syncthreads();

  #pragma unroll 1
  for (int it = 0; it < 16; it++){
    const int cur = it & 1;
    const ushort* Kc = &Ks[cur][0];
    const ushort* Vc = &Vs[cur][0];

    f32x4 s[2][4];
    #pragma unroll
    for (int fr = 0; fr < 4; fr++){
      const int row = fr*16 + l15;
      const int rx = (row & 7)*8;
      #pragma unroll
      for (int hx = 0; hx < 2; hx++){
        const s16x8 ak = *(const s16x8*)&Kc[row*64 + ((hx*32 + 8*g) ^ rx)];
        s[hx][fr] = __builtin_amdgcn_mfma_f32_16x16x32_bf16(ak, bq[hx], z4, 0,0,0);
      }
    }
    s16x8 pa[2][2];
    #pragma unroll
    for (int hx = 0; hx < 2; hx++){
      #pragma unroll
      for (int ms = 0; ms < 2; ms++){
        ushort tmp[8];
        #pragma unroll
        for (int fr2 = 0; fr2 < 2; fr2++)
          #pragma unroll
          for (int r = 0; r < 4; r++){
            const float e = __expf(s[hx][ms*2 + fr2][r] * ATT_SCALE);
            z[hx] += e;
            tmp[fr2*4 + r] = f2bf(e);
          }
        pa[hx][ms] = *(s16x8*)tmp;
      }
    }
    __builtin_amdgcn_s_setprio(1);
    #pragma unroll
    for (int ms = 0; ms < 2; ms++){
      #pragma unroll
      for (int dc = 0; dc < 4; dc++){
        const int row = dc*16 + l15;
        const int r7 = row & 7;
        const int elo = ms*32 + 4*g;
        const int eloswz = ((((elo >> 3) ^ r7) << 3) | (elo & 7));
        const int ehi = elo + 16;
        const int ehiswz = ((((ehi >> 3) ^ r7) << 3) | (ehi & 7));
        const uint2 lo = *(const uint2*)&Vc[row*64 + eloswz];
        const uint2 hi = *(const uint2*)&Vc[row*64 + ehiswz];
        union { uint u[4]; s16x8 v; } bv;
        bv.u[0] = lo.x; bv.u[1] = lo.y; bv.u[2] = hi.x; bv.u[3] = hi.y;
        o0[dc] = __builtin_amdgcn_mfma_f32_16x16x32_bf16(pa[0][ms], bv.v, o0[dc], 0,0,0);
        o1[dc] = __builtin_amdgcn_mfma_f32_16x16x32_bf16(pa[1][ms], bv.v, o1[dc], 0,0,0);
      }
    }
    __builtin_amdgcn_s_setprio(0);

    if (it < 15){
      const int nxt = cur ^ 1;
      *(uint4*)&Ks[nxt][c0row*64 + sw0] = kra;
      *(uint4*)&Ks[nxt][c1row*64 + sw1] = krb;
      *(uint4*)&Vs[nxt][c0row*64 + sw0] = vra;
      *(uint4*)&Vs[nxt][c1row*64 + sw1] = vrb;
      if (it < 14){
        const int m0 = (it + 2)*64;
        kra = *(const uint4*)&Kb[(size_t)(m0 + c0row)*64 + c0col*8];
        krb = *(const uint4*)&Kb[(size_t)(m0 + c1row)*64 + c1col*8];
        vra = *(const uint4*)&Vb[(size_t)c0row*NPIX + m0 + c0col*8];
        vrb = *(const uint4*)&Vb[(size_t)c1row*NPIX + m0 + c1col*8];
      }
    }
    __syncthreads();
  }

  #pragma unroll
  for (int hx = 0; hx < 2; hx++){
    z[hx] += __shfl_xor(z[hx], 16);
    z[hx] += __shfl_xor(z[hx], 32);
  }
  float zi0[4], zi1[4];
  #pragma unroll
  for (int r = 0; r < 4; r++){
    zi0[r] = 1.f / __shfl(z[0], 4*g + r);
    zi1[r] = 1.f / __shfl(z[1], 4*g + r);
  }
  float val[4][4];
  float ss[4] = {0.f,0.f,0.f,0.f};
  #pragma unroll
  for (int dc = 0; dc < 4; dc++)
    #pragma unroll
    for (int r = 0; r < 4; r++){
      const float vv = o0[dc][r]*zi0[r] - lam*o1[dc][r]*zi1[r];
      val[dc][r] = vv; ss[r] += vv*vv;
    }
  #pragma unroll
  for (int r = 0; r < 4; r++){
    ss[r] += __shfl_xor(ss[r], 1);
    ss[r] += __shfl_xor(ss[r], 2);
    ss[r] += __shfl_xor(ss[r], 4);
    ss[r] += __shfl_xor(ss[r], 8);
  }
  float rinv[4];
  #pragma unroll
  for (int r = 0; r < 4; r++) rinv[r] = ONE_M_LI * rsqrtf(ss[r]*(1.f/64.f) + EPSF);
  #pragma unroll
  for (int dc = 0; dc < 4; dc++){
    const float rs = Pf[1443328 + dc*16 + l15];
    #pragma unroll
    for (int r = 0; r < 4; r++){
      const int n = qsub + 4*g + r;
      att[((size_t)b*NPIX + n)*512 + h*64 + dc*16 + l15] = f2bf(val[dc][r]*rinv[r]*rs);
    }
  }
}

// ---------------- fused depthwise 3x3 + L2-norm (block = plane) ----------------
__global__ __launch_bounds__(256) void dwl2_kernel(const float* __restrict__ in,
    const float* __restrict__ wdw, float* __restrict__ out){
  __shared__ float tile[1024];
  __shared__ float wsum[4];
  const int p = blockIdx.x;                 // b*768 + c
  const int c = p % 768;
  const int t = threadIdx.x;
  const float* ip = in + (size_t)p*1024;
  *(float4*)&tile[t*4] = *(const float4*)&ip[t*4];
  float wv[9];
  #pragma unroll
  for (int i = 0; i < 9; i++) wv[i] = wdw[c*9+i];
  __syncthreads();
  float o[4]; float ssq = 0.f;
  #pragma unroll
  for (int j = 0; j < 4; j++){
    const int px = t*4 + j, x = px & 31, y = px >> 5;
    float s = 0.f;
    #pragma unroll
    for (int ky = 0; ky < 3; ky++){
      const int yy = y + ky - 1;
      if (yy < 0 || yy > 31) continue;
      #pragma unroll
      for (int kx = 0; kx < 3; kx++){
        const int xx = x + kx - 1;
        if (xx < 0 || xx > 31) continue;
        s = fmaf(tile[yy*32+xx], wv[ky*3+kx], s);
      }
    }
    o[j] = s; ssq += s*s;
  }
  for (int off = 32; off; off >>= 1) ssq += __shfl_down(ssq, off);
  if ((t & 63) == 0) wsum[t >> 6] = ssq;
  __syncthreads();
  float inv = 1.f;
  if (c < 512){
    const float tot = wsum[0]+wsum[1]+wsum[2]+wsum[3];
    inv = 1.f / fmaxf(sqrtf(tot), 1e-12f);
  }
  *(float4*)&out[(size_t)p*1024 + t*4] = make_float4(o[0]*inv, o[1]*inv, o[2]*inv, o[3]*inv);
}

// ---------------- CHA partial scores ----------------
__global__ __launch_bounds__(256) void cha_scores_kernel(const float* __restrict__ qk,
                                                         float* __restrict__ spart){
  __shared__ float qs[32][129];
  __shared__ float ks[32][129];
  const int t = threadIdx.x;
  const int nb = blockIdx.x*128;
  const int bh = blockIdx.y, b = bh >> 3, h = bh & 7;
  const size_t qbase = ((size_t)b*768 + h*32)*NPIX + nb;
  const size_t kbase = qbase + (size_t)256*NPIX;
  { const int c = t >> 3, n0 = (t & 7)*16;
    #pragma unroll
    for (int j = 0; j < 16; j++){
      qs[c][n0+j] = qk[qbase + (size_t)c*NPIX + n0 + j];
      ks[c][n0+j] = qk[kbase + (size_t)c*NPIX + n0 + j];
    } }
  __syncthreads();
  const int c = t & 31, dg = t >> 5;
  float acc[4] = {};
  for (int nn = 0; nn < 128; nn++){
    const float qv = qs[c][nn];
    #pragma unroll
    for (int j = 0; j < 4; j++) acc[j] = fmaf(qv, ks[dg*4+j][nn], acc[j]);
  }
  float* sp = spart + ((size_t)bh*8 + blockIdx.x)*1024 + c*32 + dg*4;
  #pragma unroll
  for (int j = 0; j < 4; j++) sp[j] = acc[j];
}

// ---------------- CHA softmax + PV (fused) ----------------
__global__ __launch_bounds__(256) void cha_pv_kernel(const float* __restrict__ spart,
    const float* __restrict__ tempP, const float* __restrict__ qkv, float* __restrict__ out){
  __shared__ float Ps[32][33];
  const int t = threadIdx.x;
  const int bh = blockIdx.y, b = bh >> 3, h = bh & 7;
  const int nb = blockIdx.x*64;
  const float tf = tempP[h];
  for (int p = t; p < 1024; p += 256){
    float s = 0.f;
    #pragma unroll
    for (int ch = 0; ch < 8; ch++) s += spart[((size_t)bh*8 + ch)*1024 + p];
    Ps[p >> 5][p & 31] = s * tf;
  }
  __syncthreads();
  if (t < 32){
    float mx = -1e30f;
    #pragma unroll
    for (int d = 0; d < 32; d++) mx = fmaxf(mx, Ps[t][d]);
    float sum = 0.f;
    float e[32];
    #pragma unroll
    for (int d = 0; d < 32; d++){ e[d] = __expf(Ps[t][d]-mx); sum += e[d]; }
    const float inv = 1.f/sum;
    #pragma unroll
    for (int d = 0; d < 32; d++) Ps[t][d] = e[d]*inv;
  }
  __syncthreads();
  const int n = nb + (t & 63);
  const int cg = t >> 6;
  const size_t vbase = ((size_t)b*768 + 512 + h*32)*NPIX + n;
  float acc[8] = {};
  for (int d = 0; d < 32; d++){
    const float v = qkv[vbase + (size_t)d*NPIX];
    #pragma unroll
    for (int j = 0; j < 8; j++) acc[j] = fmaf(Ps[cg*8+j][d], v, acc[j]);
  }
  const size_t obase = ((size_t)b*256 + h*32 + cg*8)*NPIX + n;
  #pragma unroll
  for (int j = 0; j < 8; j++) out[obase + (size_t)j*NPIX] = acc[j];
}

// ---------------- FFN grouped 3x3 + bias + relu6, LDS-tiled ----------------
__global__ __launch_bounds__(256) void gconv_lds_kernel(const float* __restrict__ in,
    const float* __restrict__ w, const float* __restrict__ bias, float* __restrict__ out){
  __shared__ float tin[2][1024];
  const int p = blockIdx.x;                 // b*512 + o
  const int o = p & 511, b = p >> 9;
  const int t = threadIdx.x;
  const float* ip = in + ((size_t)b*512 + (o & ~1))*1024;
  *(float4*)&tin[0][t*4] = *(const float4*)&ip[t*4];
  *(float4*)&tin[1][t*4] = *(const float4*)&ip[1024 + t*4];
  float wv[18];
  #pragma unroll
  for (int i = 0; i < 18; i++) wv[i] = w[o*18 + i];
  const float bs = bias[o];
  __syncthreads();
  float res[4];
  #pragma unroll
  for (int j = 0; j < 4; j++){
    const int px = t*4 + j, x = px & 31, y = px >> 5;
    float s = bs;
    #pragma unroll
    for (int ci = 0; ci < 2; ci++){
      #pragma unroll
      for (int ky = 0; ky < 3; ky++){
        const int yy = y + ky - 1;
        if (yy < 0 || yy > 31) continue;
        #pragma unroll
        for (int kx = 0; kx < 3; kx++){
          const int xx = x + kx - 1;
          if (xx < 0 || xx > 31) continue;
          s = fmaf(tin[ci][yy*32+xx], wv[ci*9 + ky*3 + kx], s);
        }
      }
    }
    res[j] = fminf(fmaxf(s, 0.f), 6.f);
  }
  *(float4*)&out[(size_t)p*1024 + t*4] = make_float4(res[0], res[1], res[2], res[3]);
}

extern "C" void kernel_launch(void* const* d_in, const int* in_sizes, int n_in,
                              void* d_out, int out_size, void* d_ws, size_t ws_size,
                              hipStream_t stream)
{
  (void)in_sizes; (void)n_in; (void)out_size; (void)ws_size;

  float* ws   = (float*)d_ws;
  float* P    = ws;
  float* xbuf = P;
  ushort* Wbf = (ushort*)(ws + OFF_WBF);
  ushort* QT  = (ushort*)(ws + OFF_QT);
  ushort* V16 = (ushort*)(ws + OFF_V16);
  ushort* att = (ushort*)(ws + OFF_ATT);
  float* chaout = ws + OFF_ATT;
  float* buf1 = ws + OFF_BUF1;
  float* buf2 = ws + OFF_BUF2;
  float* spart= ws + OFF_SPART;
  float* stats= ws + OFF_STATS;
  float* eff  = ws + OFF_EFF;
  int*  flag  = (int*)(ws + OFF_FLAG);

  const float* b1f = P + 1976648;
  const float* b3f = P + 2120008;
  const float* w2f = P + 1979208;
  const float* b2f_ = P + 1988424;
  const float* temp = P + 1574976;

  detect_kernel<<<1, 256, 0, stream>>>(d_in[0], flag);
  PackArgs pa;
  for (int i = 0; i < 34; i++) pa.p[i] = d_in[i];
  prep_all_kernel<<<9372, 256, 0, stream>>>(pa, flag, P, Wbf, eff, stats);

  // ---- CDA ----
  gemm_kernel<0,0,false,false,false><<<dim3(16,24,4), 256, 0, stream>>>(
      xbuf, nullptr, Wbf, nullptr, stats, stats+4096, eff, eff+256,
      nullptr, nullptr, nullptr, nullptr, QT, V16, nullptr, 256, nullptr);
  attn_kernel<<<dim3(16,8,4), 256, 0, stream>>>(QT, V16, P, eff+2560, att);
  gemm_kernel<2,1,false,false,true><<<dim3(16,4,4), 256, 0, stream>>>(
      nullptr, att, Wbf+589824, nullptr, nullptr, nullptr, nullptr, nullptr,
      nullptr, nullptr, xbuf, xbuf, nullptr, nullptr, stats+8192, 512, nullptr);

  // ---- CHA ----
  gemm_kernel<0,2,false,false,false><<<dim3(16,12,4), 256, 0, stream>>>(
      xbuf, nullptr, Wbf+393216, nullptr, stats+8192, stats+12288, eff+512, eff+768,
      nullptr, nullptr, nullptr, buf1, nullptr, nullptr, nullptr, 256, nullptr);
  dwl2_kernel<<<3072, 256, 0, stream>>>(buf1, P + 1771592, buf2);
  cha_scores_kernel<<<dim3(8,32), 256, 0, stream>>>(buf2, spart);
  cha_pv_kernel<<<dim3(16,32), 256, 0, stream>>>(spart, temp, buf2, chaout);
  gemm_kernel<1,1,false,false,true><<<dim3(16,4,4), 256, 0, stream>>>(
      chaout, nullptr, Wbf+720896, nullptr, nullptr, nullptr, nullptr, nullptr,
      nullptr, nullptr, xbuf, xbuf, nullptr, nullptr, stats+16384, 256, nullptr);

  // ---- FFN ----
  gemm_kernel<0,2,true,true,false><<<dim3(16,8,4), 256, 0, stream>>>(
      xbuf, nullptr, Wbf+786432, b1f, stats+16384, stats+20480, eff+1024, eff+1280,
      eff+1536, eff+2048, nullptr, buf1, nullptr, nullptr, nullptr, 256, nullptr);
  gconv_lds_kernel<<<2048, 256, 0, stream>>>(buf1, w2f, b2f_, buf2);
  gemm_kernel<1,3,true,false,false><<<dim3(16,4,4), 256, 0, stream>>>(
      buf2, nullptr, Wbf+917504, b3f, nullptr, nullptr, nullptr, nullptr,
      nullptr, nullptr, xbuf, d_out, nullptr, nullptr, nullptr, 512, flag);
}